// Round 1
// baseline (770.859 us; speedup 1.0000x reference)
//
#include <hip/hip_runtime.h>
#include <math.h>

#define D 66
#define GROWS 128
#define NEG_SLOPE 0.2f

__device__ __forceinline__ float lrelu(float a){ return a > 0.f ? a : NEG_SLOPE * a; }

// ---------------- BatchNorm ----------------
__global__ void k_bn_stats(const float* __restrict__ h, float* __restrict__ sums, int total){
  __shared__ float s1[D], s2[D];
  for (int i = threadIdx.x; i < D; i += blockDim.x){ s1[i] = 0.f; s2[i] = 0.f; }
  __syncthreads();
  int stride = gridDim.x * blockDim.x;
  for (int i = blockIdx.x * blockDim.x + threadIdx.x; i < total; i += stride){
    float v = h[i];
    int c = i % D;
    atomicAdd(&s1[c], v);
    atomicAdd(&s2[c], v * v);
  }
  __syncthreads();
  for (int i = threadIdx.x; i < D; i += blockDim.x){
    atomicAdd(&sums[i], s1[i]);
    atomicAdd(&sums[D + i], s2[i]);
  }
}

__global__ void k_bn_finalize(const float* __restrict__ sums,
                              const float* __restrict__ gamma, const float* __restrict__ beta,
                              const float* __restrict__ We1, const float* __restrict__ ae1,
                              const float* __restrict__ We2, const float* __restrict__ ae2,
                              const float* __restrict__ We3, const float* __restrict__ ae3,
                              float* __restrict__ misc, int n){
  int t = threadIdx.x;
  if (t < D){
    float mean = sums[t] / (float)n;
    float var  = sums[D + t] / (float)n - mean * mean;
    float inv  = rsqrtf(var + 1e-5f);
    float sc = gamma[t] * inv;
    misc[t] = sc;
    misc[D + t] = beta[t] - mean * sc;
  } else if (t == D){
    float c = 0.f; for (int d = 0; d < D; d++) c += We1[d] * ae1[d]; misc[2*D + 0] = c;
  } else if (t == D + 1){
    float c = 0.f; for (int d = 0; d < D; d++) c += We2[d] * ae2[d]; misc[2*D + 1] = c;
  } else if (t == D + 2){
    float c = 0.f; for (int d = 0; d < D; d++) c += We3[d] * ae3[d]; misc[2*D + 2] = c;
  }
}

__global__ void k_bn_apply(const float* __restrict__ h, const float* __restrict__ misc,
                           float* __restrict__ x, int total){
  int i = blockIdx.x * blockDim.x + threadIdx.x;
  if (i >= total) return;
  int c = i % D;
  x[i] = h[i] * misc[c] + misc[D + c];
}

// ---------------- CSR build (by dst) ----------------
__global__ void k_deg(const int* __restrict__ dst, int* __restrict__ deg, int E){
  int e = blockIdx.x * blockDim.x + threadIdx.x;
  if (e < E) atomicAdd(&deg[dst[e]], 1);
}

__global__ void k_scan1(const int* __restrict__ deg, int* __restrict__ bsum, int n){
  __shared__ int sh[256];
  int i = blockIdx.x * 256 + threadIdx.x;
  sh[threadIdx.x] = (i < n) ? deg[i] : 0;
  __syncthreads();
  for (int off = 128; off; off >>= 1){
    if (threadIdx.x < off) sh[threadIdx.x] += sh[threadIdx.x + off];
    __syncthreads();
  }
  if (threadIdx.x == 0) bsum[blockIdx.x] = sh[0];
}

__global__ void k_scan2(const int* __restrict__ bsum, int* __restrict__ boff,
                        int* __restrict__ rowptr, int nb, int n){
  __shared__ int sh[256];
  int t = threadIdx.x;
  int v = (t < nb) ? bsum[t] : 0;
  sh[t] = v; __syncthreads();
  for (int off = 1; off < 256; off <<= 1){
    int u = (t >= off) ? sh[t - off] : 0;
    __syncthreads();
    sh[t] += u;
    __syncthreads();
  }
  if (t < nb) boff[t] = sh[t] - v;      // exclusive offsets per block
  if (t == 255) rowptr[n] = sh[255];    // total edge count
}

__global__ void k_scan3(const int* __restrict__ deg, const int* __restrict__ boff,
                        int* __restrict__ rowptr, int n){
  __shared__ int sh[256];
  int t = threadIdx.x;
  int i = blockIdx.x * 256 + t;
  int v = (i < n) ? deg[i] : 0;
  sh[t] = v; __syncthreads();
  for (int off = 1; off < 256; off <<= 1){
    int u = (t >= off) ? sh[t - off] : 0;
    __syncthreads();
    sh[t] += u;
    __syncthreads();
  }
  if (i < n) rowptr[i] = boff[blockIdx.x] + sh[t] - v;   // exclusive scan
}

__global__ void k_fill(const int* __restrict__ src, const int* __restrict__ dst,
                       const float* __restrict__ ew, const int* __restrict__ rowptr,
                       int* __restrict__ cursor, int* __restrict__ csrc,
                       float* __restrict__ cew, int E){
  int e = blockIdx.x * blockDim.x + threadIdx.x;
  if (e >= E) return;
  int d = dst[e];
  int pos = atomicAdd(&cursor[d], 1);
  int slot = rowptr[d] + pos;
  csrc[slot] = src[e];
  cew[slot]  = ew[e];
}

// ---------------- GEMM: out = xin @ W (+bias, relu); GAT variant adds att dots ----------------
template<int NCOL, bool RELU, bool GAT>
__global__ __launch_bounds__(256) void k_gemm(const float* __restrict__ xin, const float* __restrict__ W,
                                              const float* __restrict__ bias,
                                              const float* __restrict__ att_s, const float* __restrict__ att_d,
                                              float* __restrict__ out,
                                              float* __restrict__ a_src, float* __restrict__ a_dst, int n){
  constexpr int CH = (NCOL + 1) / 2;
  __shared__ float Ws[D * NCOL];
  __shared__ float xs[GROWS * (D + 1)];   // +1 pad: lane-stride 67 -> 2-way bank alias (free)
  __shared__ float ps_[GROWS * 2], pd_[GROWS * 2];
  int tid = threadIdx.x;
  int row0 = blockIdx.x * GROWS;
  for (int i = tid; i < D * NCOL; i += 256) Ws[i] = W[i];
  int nr = min(GROWS, n - row0);
  for (int i = tid; i < nr * D; i += 256){
    int r = i / D, k = i - r * D;
    xs[r * (D + 1) + k] = xin[(size_t)(row0 + r) * D + k];
  }
  __syncthreads();
  int r = tid & (GROWS - 1);
  int half = tid >> 7;
  int c0 = half * CH;
  float acc[CH];
  #pragma unroll
  for (int j = 0; j < CH; j++) acc[j] = 0.f;
  if (r < nr){
    const float* xr = &xs[r * (D + 1)];
    for (int k = 0; k < D; k++){
      float xv = xr[k];
      const float* wr = &Ws[k * NCOL + c0];   // wave-uniform address -> LDS broadcast
      #pragma unroll
      for (int j = 0; j < CH; j++) acc[j] += xv * wr[j];
    }
  }
  float ps = 0.f, pd = 0.f;
  if (r < nr){
    size_t off = (size_t)(row0 + r) * NCOL + c0;
    #pragma unroll
    for (int j = 0; j < CH; j++){
      float v = acc[j] + (GAT ? 0.f : bias[c0 + j]);
      if (RELU) v = v > 0.f ? v : 0.f;
      out[off + j] = v;
      if (GAT){ ps += acc[j] * att_s[c0 + j]; pd += acc[j] * att_d[c0 + j]; }
    }
  }
  if (GAT){
    ps_[half * GROWS + r] = ps;
    pd_[half * GROWS + r] = pd;
    __syncthreads();
    if (half == 0 && r < nr){
      a_src[row0 + r] = ps_[r] + ps_[GROWS + r];
      a_dst[row0 + r] = pd_[r] + pd_[GROWS + r];
    }
  }
}

// ---------------- GAT edge softmax + aggregate: one wave per dst node ----------------
__global__ __launch_bounds__(256) void k_agg(const float* __restrict__ y,
                                             const float* __restrict__ a_src, const float* __restrict__ a_dst,
                                             const int* __restrict__ rowptr, const int* __restrict__ csrc,
                                             const float* __restrict__ cew,
                                             const float* __restrict__ misc, int cidx,
                                             const float* __restrict__ bias,
                                             float* __restrict__ xout, int n){
  int wave = (int)((blockIdx.x * blockDim.x + threadIdx.x) >> 6);
  int lane = threadIdx.x & 63;
  if (wave >= n) return;
  int beg = rowptr[wave], end = rowptr[wave + 1];
  int deg = end - beg;
  float c = misc[2 * D + cidx];
  float adn = a_dst[wave];

  // pass A: segment max of leakyrelu(alpha)
  float m = -INFINITY;
  for (int j0 = 0; j0 < deg; j0 += 64){
    int j = j0 + lane;
    float al = -INFINITY;
    if (j < deg){
      float a = a_src[csrc[beg + j]] + adn + c * cew[beg + j];
      al = lrelu(a);
    }
    m = fmaxf(m, al);
  }
  #pragma unroll
  for (int off = 32; off; off >>= 1) m = fmaxf(m, __shfl_xor(m, off));

  // pass B: denom
  float dsum = 0.f;
  for (int j0 = 0; j0 < deg; j0 += 64){
    int j = j0 + lane;
    if (j < deg){
      float a = a_src[csrc[beg + j]] + adn + c * cew[beg + j];
      dsum += __expf(lrelu(a) - m);
    }
  }
  #pragma unroll
  for (int off = 32; off; off >>= 1) dsum += __shfl_xor(dsum, off);
  float inv = 1.f / (dsum + 1e-16f);

  // pass C: weighted gather-accumulate of y[src,:]
  float acc0 = 0.f, acc1 = 0.f;
  for (int j0 = 0; j0 < deg; j0 += 64){
    int cnt = min(64, deg - j0);
    int j = j0 + lane;
    int s = 0; float coef = 0.f;
    if (j < deg){
      s = csrc[beg + j];
      float a = a_src[s] + adn + c * cew[beg + j];
      coef = __expf(lrelu(a) - m) * inv;
    }
    for (int t = 0; t < cnt; t++){
      int   st = __shfl(s, t);
      float ct = __shfl(coef, t);
      const float* row = y + (size_t)st * D;
      acc0 += ct * row[lane];
      if (lane < 2) acc1 += ct * row[64 + lane];
    }
  }
  float* orow = xout + (size_t)wave * D;
  float v0 = acc0 + bias[lane];
  orow[lane] = v0 > 0.f ? v0 : 0.f;
  if (lane < 2){
    float v1 = acc1 + bias[64 + lane];
    orow[64 + lane] = v1 > 0.f ? v1 : 0.f;
  }
}

// ---------------- launch ----------------
extern "C" void kernel_launch(void* const* d_in, const int* in_sizes, int n_in,
                              void* d_out, int out_size, void* d_ws, size_t ws_size,
                              hipStream_t stream){
  const float* h     = (const float*)d_in[0];
  const int*   ei    = (const int*)  d_in[1];
  const float* ew    = (const float*)d_in[2];
  const float* gamma = (const float*)d_in[3];
  const float* beta  = (const float*)d_in[4];
  const float *Wl[3], *bl[3], *asl[3], *adl[3], *Wel[3], *ael[3];
  int idx = 5;
  for (int l = 0; l < 3; l++){
    Wl[l]  = (const float*)d_in[idx++];
    bl[l]  = (const float*)d_in[idx++];
    asl[l] = (const float*)d_in[idx++];
    adl[l] = (const float*)d_in[idx++];
    Wel[l] = (const float*)d_in[idx++];
    ael[l] = (const float*)d_in[idx++];
  }
  const float *fw[5], *fb[5];
  for (int l = 0; l < 5; l++){ fw[l] = (const float*)d_in[idx++]; fb[l] = (const float*)d_in[idx++]; }

  int N = in_sizes[0] / D;
  int E = in_sizes[1] / 2;
  const int* src  = ei;
  const int* dstp = ei + E;

  char* base = (char*)d_ws;
  size_t o = 0;
  auto alloc = [&](size_t b){ size_t r = o; o += (b + 255) & ~(size_t)255; return r; };
  float* bufA   = (float*)(base + alloc((size_t)N * D * 4));
  float* bufB   = (float*)(base + alloc((size_t)N * D * 4));
  float* a_src  = (float*)(base + alloc((size_t)N * 4));
  float* a_dst  = (float*)(base + alloc((size_t)N * 4));
  float* misc   = (float*)(base + alloc(512 * 4));
  float* sums   = (float*)(base + alloc(132 * 4));
  int*   deg    = (int*)  (base + alloc((size_t)N * 4));
  int*   cursor = (int*)  (base + alloc((size_t)N * 4));
  int*   rowptr = (int*)  (base + alloc((size_t)(N + 1) * 4));
  int*   bsum   = (int*)  (base + alloc(1024));
  int*   boff   = (int*)  (base + alloc(1024));
  int*   csrc   = (int*)  (base + alloc((size_t)E * 4));
  float* cew    = (float*)(base + alloc((size_t)E * 4));

  hipMemsetAsync(sums, 0, 132 * 4, stream);
  hipMemsetAsync(deg, 0, (size_t)N * 4, stream);
  hipMemsetAsync(cursor, 0, (size_t)N * 4, stream);

  int total = N * D;
  k_bn_stats<<<512, 256, 0, stream>>>(h, sums, total);
  k_bn_finalize<<<1, 128, 0, stream>>>(sums, gamma, beta, Wel[0], ael[0], Wel[1], ael[1], Wel[2], ael[2], misc, N);
  k_bn_apply<<<(total + 255) / 256, 256, 0, stream>>>(h, misc, bufA, total);

  k_deg<<<(E + 255) / 256, 256, 0, stream>>>(dstp, deg, E);
  int nb = (N + 255) / 256;
  k_scan1<<<nb, 256, 0, stream>>>(deg, bsum, N);
  k_scan2<<<1, 256, 0, stream>>>(bsum, boff, rowptr, nb, N);
  k_scan3<<<nb, 256, 0, stream>>>(deg, boff, rowptr, N);
  k_fill<<<(E + 255) / 256, 256, 0, stream>>>(src, dstp, ew, rowptr, cursor, csrc, cew, E);

  int gb = (N + GROWS - 1) / GROWS;
  for (int l = 0; l < 3; l++){
    k_gemm<D, false, true><<<gb, 256, 0, stream>>>(bufA, Wl[l], nullptr, asl[l], adl[l], bufB, a_src, a_dst, N);
    k_agg<<<(N * 64 + 255) / 256, 256, 0, stream>>>(bufB, a_src, a_dst, rowptr, csrc, cew, misc, l, bl[l], bufA, N);
  }
  k_gemm<D, true, false><<<gb, 256, 0, stream>>>(bufA, fw[0], fb[0], nullptr, nullptr, bufB, nullptr, nullptr, N);
  k_gemm<D, true, false><<<gb, 256, 0, stream>>>(bufB, fw[1], fb[1], nullptr, nullptr, bufA, nullptr, nullptr, N);
  k_gemm<D, true, false><<<gb, 256, 0, stream>>>(bufA, fw[2], fb[2], nullptr, nullptr, bufB, nullptr, nullptr, N);
  k_gemm<D, true, false><<<gb, 256, 0, stream>>>(bufB, fw[3], fb[3], nullptr, nullptr, bufA, nullptr, nullptr, N);
  k_gemm<22, false, false><<<gb, 256, 0, stream>>>(bufA, fw[4], fb[4], nullptr, nullptr, (float*)d_out, nullptr, nullptr, N);
}

// Round 2
// 596.844 us; speedup vs baseline: 1.2916x; 1.2916x over previous
//
#include <hip/hip_runtime.h>
#include <math.h>

#define D 66
#define SP 68                 // padded row stride (floats), 16B-aligned rows
#define NEG_SLOPE 0.2f

__device__ __forceinline__ float lrelu(float a){ return a > 0.f ? a : NEG_SLOPE * a; }
__device__ __forceinline__ void fma4(float4& a, float s, const float4& w){
  a.x = fmaf(s, w.x, a.x); a.y = fmaf(s, w.y, a.y);
  a.z = fmaf(s, w.z, a.z); a.w = fmaf(s, w.w, a.w);
}

// ---------------- BatchNorm stats ----------------
__global__ __launch_bounds__(256) void k_bn_stats(const float* __restrict__ h,
                                                  float* __restrict__ sums, int n){
  __shared__ float ls[2 * D];
  int t = threadIdx.x;
  if (t < 2 * D) ls[t] = 0.f;
  __syncthreads();
  int rpb = (n + gridDim.x - 1) / gridDim.x;
  int r0 = blockIdx.x * rpb;
  int r1 = min(n, r0 + rpb);
  if (t < 3 * D){
    int c = t % D, seg = t / D;
    float s1 = 0.f, s2 = 0.f;
    for (int r = r0 + seg; r < r1; r += 3){
      float v = h[(size_t)r * D + c];
      s1 += v; s2 += v * v;
    }
    atomicAdd(&ls[c], s1);
    atomicAdd(&ls[D + c], s2);
  }
  __syncthreads();
  if (t < 2 * D) atomicAdd(&sums[t], ls[t]);
}

__global__ void k_bn_finalize(const float* __restrict__ sums,
                              const float* __restrict__ gamma, const float* __restrict__ beta,
                              const float* __restrict__ We1, const float* __restrict__ ae1,
                              const float* __restrict__ We2, const float* __restrict__ ae2,
                              const float* __restrict__ We3, const float* __restrict__ ae3,
                              float* __restrict__ misc, int n){
  int t = threadIdx.x;
  if (t < D){
    float mean = sums[t] / (float)n;
    float var  = sums[D + t] / (float)n - mean * mean;
    float inv  = rsqrtf(var + 1e-5f);
    float sc = gamma[t] * inv;
    misc[t] = sc;
    misc[D + t] = beta[t] - mean * sc;
  } else if (t == D){
    float c = 0.f; for (int d = 0; d < D; d++) c += We1[d] * ae1[d]; misc[2*D + 0] = c;
  } else if (t == D + 1){
    float c = 0.f; for (int d = 0; d < D; d++) c += We2[d] * ae2[d]; misc[2*D + 1] = c;
  } else if (t == D + 2){
    float c = 0.f; for (int d = 0; d < D; d++) c += We3[d] * ae3[d]; misc[2*D + 2] = c;
  }
}

// ---------------- CSR build (by dst) ----------------
__global__ void k_deg(const int* __restrict__ dst, int* __restrict__ deg, int E){
  int e = blockIdx.x * blockDim.x + threadIdx.x;
  if (e < E) atomicAdd(&deg[dst[e]], 1);
}

__global__ void k_scan1(const int* __restrict__ deg, int* __restrict__ bsum, int n){
  __shared__ int sh[256];
  int i = blockIdx.x * 256 + threadIdx.x;
  sh[threadIdx.x] = (i < n) ? deg[i] : 0;
  __syncthreads();
  for (int off = 128; off; off >>= 1){
    if (threadIdx.x < off) sh[threadIdx.x] += sh[threadIdx.x + off];
    __syncthreads();
  }
  if (threadIdx.x == 0) bsum[blockIdx.x] = sh[0];
}

__global__ void k_scan2(const int* __restrict__ bsum, int* __restrict__ boff,
                        int* __restrict__ rowptr, int nb, int n){
  __shared__ int sh[256];
  int t = threadIdx.x;
  int v = (t < nb) ? bsum[t] : 0;
  sh[t] = v; __syncthreads();
  for (int off = 1; off < 256; off <<= 1){
    int u = (t >= off) ? sh[t - off] : 0;
    __syncthreads();
    sh[t] += u;
    __syncthreads();
  }
  if (t < nb) boff[t] = sh[t] - v;
  if (t == 255) rowptr[n] = sh[255];
}

__global__ void k_scan3(const int* __restrict__ deg, const int* __restrict__ boff,
                        int* __restrict__ rowptr, int n){
  __shared__ int sh[256];
  int t = threadIdx.x;
  int i = blockIdx.x * 256 + t;
  int v = (i < n) ? deg[i] : 0;
  sh[t] = v; __syncthreads();
  for (int off = 1; off < 256; off <<= 1){
    int u = (t >= off) ? sh[t - off] : 0;
    __syncthreads();
    sh[t] += u;
    __syncthreads();
  }
  if (i < n) rowptr[i] = boff[blockIdx.x] + sh[t] - v;
}

__global__ void k_fill(const int* __restrict__ src, const int* __restrict__ dst,
                       const float* __restrict__ ew, const int* __restrict__ rowptr,
                       int* __restrict__ cursor, int2* __restrict__ epair, int E){
  int e = blockIdx.x * blockDim.x + threadIdx.x;
  if (e >= E) return;
  int d = dst[e];
  int pos = atomicAdd(&cursor[d], 1);
  int slot = rowptr[d] + pos;
  epair[slot] = make_int2(src[e], __float_as_int(ew[e]));
}

// ---------------- GEMM ----------------
// MODE 0 = GAT raw out (no bias/relu) + att dots; 1 = relu(x@W+b), padded out;
// MODE 2 = x@W+b, compact out stride = ncol.
template<int CQ, int RG, int MODE, bool BN_IN>
__global__ __launch_bounds__(256) void k_gemm(const float* __restrict__ xin, int in_stride,
                                              const float* __restrict__ W, int ncol,
                                              const float* __restrict__ bias,
                                              const float* __restrict__ att_s, const float* __restrict__ att_d,
                                              const float* __restrict__ bn_misc,
                                              float* __restrict__ out,
                                              float* __restrict__ a_src, float* __restrict__ a_dst, int n){
  constexpr int NT  = CQ * RG;
  constexpr int RB  = RG * 4;
  constexpr int CQ4 = CQ * 4;
  __shared__ float xs[RB * SP];
  __shared__ float Ws[SP * CQ4];
  const int t = threadIdx.x;
  const int row0 = blockIdx.x * RB;

  if (t < NT){
    for (int f = t; f < SP * CQ4; f += NT){
      int k = f / CQ4, c = f % CQ4;
      Ws[f] = (k < D && c < ncol) ? W[k * ncol + c] : 0.f;
    }
    if (BN_IN){
      for (int f = t; f < RB * (SP/2); f += NT){
        int r = f / (SP/2), c = 2 * (f % (SP/2));
        float2 v = make_float2(0.f, 0.f);
        if (row0 + r < n && c < D){
          float2 hv = *(const float2*)&xin[(size_t)(row0 + r) * in_stride + c];
          v.x = hv.x * bn_misc[c]     + bn_misc[D + c];
          v.y = hv.y * bn_misc[c + 1] + bn_misc[D + c + 1];
        }
        *(float2*)&xs[r * SP + c] = v;
      }
    } else {
      for (int f = t; f < RB * (SP/4); f += NT){
        int r = f / (SP/4), q = f % (SP/4);
        float4 v = make_float4(0.f, 0.f, 0.f, 0.f);
        if (row0 + r < n) v = *(const float4*)&xin[(size_t)(row0 + r) * in_stride + 4 * q];
        *(float4*)&xs[r * SP + 4 * q] = v;
      }
    }
  }
  __syncthreads();

  const int ry = t / CQ, cq = t % CQ;
  float4 acc[4];
  #pragma unroll
  for (int i = 0; i < 4; i++) acc[i] = make_float4(0.f, 0.f, 0.f, 0.f);

  if (t < NT){
    for (int kc = 0; kc < SP / 4; kc++){
      int k0 = kc * 4;
      float4 w0 = *(const float4*)&Ws[(k0 + 0) * CQ4 + 4 * cq];
      float4 w1 = *(const float4*)&Ws[(k0 + 1) * CQ4 + 4 * cq];
      float4 w2 = *(const float4*)&Ws[(k0 + 2) * CQ4 + 4 * cq];
      float4 w3 = *(const float4*)&Ws[(k0 + 3) * CQ4 + 4 * cq];
      #pragma unroll
      for (int i = 0; i < 4; i++){
        float4 xv = *(const float4*)&xs[(ry * 4 + i) * SP + k0];
        fma4(acc[i], xv.x, w0);
        fma4(acc[i], xv.y, w1);
        fma4(acc[i], xv.z, w2);
        fma4(acc[i], xv.w, w3);
      }
    }
  }

  float ps[4] = {0.f,0.f,0.f,0.f}, pd[4] = {0.f,0.f,0.f,0.f};
  if (t < NT){
    #pragma unroll
    for (int i = 0; i < 4; i++){
      int row = row0 + ry * 4 + i;
      if (row >= n) continue;
      const float* ai = (const float*)&acc[i];
      if (MODE == 2){
        #pragma unroll
        for (int j = 0; j < 4; j++){
          int c = 4 * cq + j;
          if (c < ncol) out[(size_t)row * ncol + c] = ai[j] + bias[c];
        }
      } else {
        float4 v; float* vp = (float*)&v;
        #pragma unroll
        for (int j = 0; j < 4; j++){
          int c = 4 * cq + j;
          float o = 0.f;
          if (c < D){
            float a = ai[j];
            if (MODE == 1){ a += bias[c]; a = a > 0.f ? a : 0.f; }
            else { ps[i] += a * att_s[c]; pd[i] += a * att_d[c]; }
            o = a;
          }
          vp[j] = o;
        }
        *(float4*)&out[(size_t)row * SP + 4 * cq] = v;
      }
    }
  }

  if (MODE == 0){
    __syncthreads();                 // xs no longer needed; reuse for att partials
    float* pss = xs;
    float* psd = xs + RB * CQ;
    if (t < NT){
      #pragma unroll
      for (int i = 0; i < 4; i++){
        pss[(ry * 4 + i) * CQ + cq] = ps[i];
        psd[(ry * 4 + i) * CQ + cq] = pd[i];
      }
    }
    __syncthreads();
    for (int r = t; r < RB; r += blockDim.x){
      if (row0 + r < n){
        float s = 0.f, d2 = 0.f;
        for (int q = 0; q < CQ; q++){ s += pss[r * CQ + q]; d2 += psd[r * CQ + q]; }
        a_src[row0 + r] = s;
        a_dst[row0 + r] = d2;
      }
    }
  }
}

// ---------------- GAT softmax + aggregate: one wave per dst node ----------------
__global__ __launch_bounds__(256) void k_agg(const float* __restrict__ y,
                                             const float* __restrict__ a_src, const float* __restrict__ a_dst,
                                             const int* __restrict__ rowptr, const int2* __restrict__ epair,
                                             const float* __restrict__ misc, int cidx,
                                             const float* __restrict__ bias,
                                             float* __restrict__ xout, int n){
  const int wid  = (int)((blockIdx.x * (size_t)blockDim.x + threadIdx.x) >> 6);
  const int lane = threadIdx.x & 63;
  if (wid >= n) return;
  const int beg = rowptr[wid];
  const int deg = rowptr[wid + 1] - beg;
  const float ce  = misc[2 * D + cidx];
  const float adn = a_dst[wid];
  const int g = lane >> 4, q = lane & 15;

  float4 vacc = make_float4(0.f, 0.f, 0.f, 0.f);
  float2 tacc = make_float2(0.f, 0.f);

  if (deg <= 64){
    // single-pass register softmax
    int s = 0; float al = -INFINITY;
    bool act = lane < deg;
    if (act){
      int2 ep = epair[beg + lane];
      s = ep.x;
      al = lrelu(a_src[s] + adn + ce * __int_as_float(ep.y));
    }
    float m = al;
    #pragma unroll
    for (int o = 32; o; o >>= 1) m = fmaxf(m, __shfl_xor(m, o));
    float ex = act ? __expf(al - m) : 0.f;
    float sum = ex;
    #pragma unroll
    for (int o = 32; o; o >>= 1) sum += __shfl_xor(sum, o);
    float coef = ex * (1.f / (sum + 1e-16f));
    for (int e0 = 0; e0 < deg; e0 += 4){
      int e = e0 + g;
      int   st = __shfl(s, e);
      float ct = __shfl(coef, e);        // lanes >= deg hold coef = 0
      const float* row = y + (size_t)st * SP;
      float4 yv = *(const float4*)&row[4 * q];
      fma4(vacc, ct, yv);
      if (q == 0){
        float2 tv = *(const float2*)&row[64];
        tacc.x += ct * tv.x; tacc.y += ct * tv.y;
      }
    }
  } else {
    float m = -INFINITY;
    for (int j0 = 0; j0 < deg; j0 += 64){
      int j = j0 + lane;
      if (j < deg){
        int2 ep = epair[beg + j];
        m = fmaxf(m, lrelu(a_src[ep.x] + adn + ce * __int_as_float(ep.y)));
      }
    }
    #pragma unroll
    for (int o = 32; o; o >>= 1) m = fmaxf(m, __shfl_xor(m, o));
    float sum = 0.f;
    for (int j0 = 0; j0 < deg; j0 += 64){
      int j = j0 + lane;
      if (j < deg){
        int2 ep = epair[beg + j];
        sum += __expf(lrelu(a_src[ep.x] + adn + ce * __int_as_float(ep.y)) - m);
      }
    }
    #pragma unroll
    for (int o = 32; o; o >>= 1) sum += __shfl_xor(sum, o);
    float inv = 1.f / (sum + 1e-16f);
    for (int j0 = 0; j0 < deg; j0 += 64){
      int cnt = min(64, deg - j0);
      int s = 0; float coef = 0.f;
      if (lane < cnt){
        int2 ep = epair[beg + j0 + lane];
        s = ep.x;
        coef = __expf(lrelu(a_src[s] + adn + ce * __int_as_float(ep.y)) - m) * inv;
      }
      for (int e0 = 0; e0 < cnt; e0 += 4){
        int e = e0 + g;
        int   st = __shfl(s, e);
        float ct = __shfl(coef, e);
        const float* row = y + (size_t)st * SP;
        float4 yv = *(const float4*)&row[4 * q];
        fma4(vacc, ct, yv);
        if (q == 0){
          float2 tv = *(const float2*)&row[64];
          tacc.x += ct * tv.x; tacc.y += ct * tv.y;
        }
      }
    }
  }

  // reduce the 4 edge-groups
  #pragma unroll
  for (int o = 16; o <= 32; o <<= 1){
    vacc.x += __shfl_xor(vacc.x, o);
    vacc.y += __shfl_xor(vacc.y, o);
    vacc.z += __shfl_xor(vacc.z, o);
    vacc.w += __shfl_xor(vacc.w, o);
    tacc.x += __shfl_xor(tacc.x, o);
    tacc.y += __shfl_xor(tacc.y, o);
  }
  float* orow = xout + (size_t)wid * SP;
  if (lane < 16){
    float4 v;
    v.x = vacc.x + bias[4*lane+0]; v.x = v.x > 0.f ? v.x : 0.f;
    v.y = vacc.y + bias[4*lane+1]; v.y = v.y > 0.f ? v.y : 0.f;
    v.z = vacc.z + bias[4*lane+2]; v.z = v.z > 0.f ? v.z : 0.f;
    v.w = vacc.w + bias[4*lane+3]; v.w = v.w > 0.f ? v.w : 0.f;
    *(float4*)&orow[4 * lane] = v;
  }
  if (lane == 0){
    float4 tv;
    tv.x = tacc.x + bias[64]; tv.x = tv.x > 0.f ? tv.x : 0.f;
    tv.y = tacc.y + bias[65]; tv.y = tv.y > 0.f ? tv.y : 0.f;
    tv.z = 0.f; tv.w = 0.f;
    *(float4*)&orow[64] = tv;
  }
}

// ---------------- launch ----------------
extern "C" void kernel_launch(void* const* d_in, const int* in_sizes, int n_in,
                              void* d_out, int out_size, void* d_ws, size_t ws_size,
                              hipStream_t stream){
  const float* h     = (const float*)d_in[0];
  const int*   ei    = (const int*)  d_in[1];
  const float* ew    = (const float*)d_in[2];
  const float* gamma = (const float*)d_in[3];
  const float* beta  = (const float*)d_in[4];
  const float *Wl[3], *bl[3], *asl[3], *adl[3], *Wel[3], *ael[3];
  int idx = 5;
  for (int l = 0; l < 3; l++){
    Wl[l]  = (const float*)d_in[idx++];
    bl[l]  = (const float*)d_in[idx++];
    asl[l] = (const float*)d_in[idx++];
    adl[l] = (const float*)d_in[idx++];
    Wel[l] = (const float*)d_in[idx++];
    ael[l] = (const float*)d_in[idx++];
  }
  const float *fw[5], *fb[5];
  for (int l = 0; l < 5; l++){ fw[l] = (const float*)d_in[idx++]; fb[l] = (const float*)d_in[idx++]; }

  int N = in_sizes[0] / D;
  int E = in_sizes[1] / 2;
  const int* src  = ei;
  const int* dstp = ei + E;

  char* base = (char*)d_ws;
  size_t o = 0;
  auto alloc = [&](size_t b){ size_t r = o; o += (b + 255) & ~(size_t)255; return r; };
  float* bufA   = (float*)(base + alloc((size_t)N * SP * 4));
  float* bufB   = (float*)(base + alloc((size_t)N * SP * 4));
  float* a_src  = (float*)(base + alloc((size_t)N * 4));
  float* a_dst  = (float*)(base + alloc((size_t)N * 4));
  float* misc   = (float*)(base + alloc(512 * 4));
  float* sums   = (float*)(base + alloc(2 * D * 4));
  int*   deg    = (int*)  (base + alloc((size_t)N * 4));
  int*   cursor = (int*)  (base + alloc((size_t)N * 4));
  int*   rowptr = (int*)  (base + alloc((size_t)(N + 1) * 4));
  int*   bsum   = (int*)  (base + alloc(1024));
  int*   boff   = (int*)  (base + alloc(1024));
  int2*  epair  = (int2*) (base + alloc((size_t)E * 8));

  hipMemsetAsync(sums, 0, 2 * D * 4, stream);
  hipMemsetAsync(deg, 0, (size_t)N * 4, stream);
  hipMemsetAsync(cursor, 0, (size_t)N * 4, stream);

  k_bn_stats<<<256, 256, 0, stream>>>(h, sums, N);
  k_bn_finalize<<<1, 128, 0, stream>>>(sums, gamma, beta, Wel[0], ael[0], Wel[1], ael[1], Wel[2], ael[2], misc, N);

  k_deg<<<(E + 255) / 256, 256, 0, stream>>>(dstp, deg, E);
  int nb = (N + 255) / 256;
  k_scan1<<<nb, 256, 0, stream>>>(deg, bsum, N);
  k_scan2<<<1, 256, 0, stream>>>(bsum, boff, rowptr, nb, N);
  k_scan3<<<nb, 256, 0, stream>>>(deg, boff, rowptr, N);
  k_fill<<<(E + 255) / 256, 256, 0, stream>>>(src, dstp, ew, rowptr, cursor, epair, E);

  constexpr int RB17 = 60;    // CQ=17, RG=15
  int gb = (N + RB17 - 1) / RB17;
  int ab = (N + 3) / 4;       // one wave per node

  // GAT layer 1 (BN fused into staging) then layers 2,3
  k_gemm<17,15,0,true ><<<gb, 256, 0, stream>>>(h,    D,  Wl[0], D, nullptr, asl[0], adl[0], misc, bufB, a_src, a_dst, N);
  k_agg<<<ab, 256, 0, stream>>>(bufB, a_src, a_dst, rowptr, epair, misc, 0, bl[0], bufA, N);
  k_gemm<17,15,0,false><<<gb, 256, 0, stream>>>(bufA, SP, Wl[1], D, nullptr, asl[1], adl[1], misc, bufB, a_src, a_dst, N);
  k_agg<<<ab, 256, 0, stream>>>(bufB, a_src, a_dst, rowptr, epair, misc, 1, bl[1], bufA, N);
  k_gemm<17,15,0,false><<<gb, 256, 0, stream>>>(bufA, SP, Wl[2], D, nullptr, asl[2], adl[2], misc, bufB, a_src, a_dst, N);
  k_agg<<<ab, 256, 0, stream>>>(bufB, a_src, a_dst, rowptr, epair, misc, 2, bl[2], bufA, N);

  // FC head
  k_gemm<17,15,1,false><<<gb, 256, 0, stream>>>(bufA, SP, fw[0], D, fb[0], nullptr, nullptr, nullptr, bufB, nullptr, nullptr, N);
  k_gemm<17,15,1,false><<<gb, 256, 0, stream>>>(bufB, SP, fw[1], D, fb[1], nullptr, nullptr, nullptr, bufA, nullptr, nullptr, N);
  k_gemm<17,15,1,false><<<gb, 256, 0, stream>>>(bufA, SP, fw[2], D, fb[2], nullptr, nullptr, nullptr, bufB, nullptr, nullptr, N);
  k_gemm<17,15,1,false><<<gb, 256, 0, stream>>>(bufB, SP, fw[3], D, fb[3], nullptr, nullptr, nullptr, bufA, nullptr, nullptr, N);
  constexpr int RB6 = 168;    // CQ=6, RG=42
  k_gemm<6,42,2,false><<<(N + RB6 - 1) / RB6, 256, 0, stream>>>(bufA, SP, fw[4], 22, fb[4], nullptr, nullptr, nullptr, (float*)d_out, nullptr, nullptr, N);
}

// Round 3
// 517.361 us; speedup vs baseline: 1.4900x; 1.1536x over previous
//
#include <hip/hip_runtime.h>
#include <math.h>

#define D 66
#define SP 68                 // padded row stride (floats), 16B-aligned rows
#define NEG_SLOPE 0.2f
#define CAP 6144              // max bucket edges staged in LDS (uniform ~5120)

__device__ __forceinline__ float lrelu(float a){ return a > 0.f ? a : NEG_SLOPE * a; }
__device__ __forceinline__ void fma4(float4& a, float s, const float4& w){
  a.x = fmaf(s, w.x, a.x); a.y = fmaf(s, w.y, a.y);
  a.z = fmaf(s, w.z, a.z); a.w = fmaf(s, w.w, a.w);
}

// ---------------- BatchNorm stats ----------------
__global__ __launch_bounds__(256) void k_bn_stats(const float* __restrict__ h,
                                                  float* __restrict__ sums, int n){
  __shared__ float ls[2 * D];
  int t = threadIdx.x;
  if (t < 2 * D) ls[t] = 0.f;
  __syncthreads();
  int rpb = (n + gridDim.x - 1) / gridDim.x;
  int r0 = blockIdx.x * rpb;
  int r1 = min(n, r0 + rpb);
  if (t < 3 * D){
    int c = t % D, seg = t / D;
    float s1 = 0.f, s2 = 0.f;
    for (int r = r0 + seg; r < r1; r += 3){
      float v = h[(size_t)r * D + c];
      s1 += v; s2 += v * v;
    }
    atomicAdd(&ls[c], s1);
    atomicAdd(&ls[D + c], s2);
  }
  __syncthreads();
  if (t < 2 * D) atomicAdd(&sums[t], ls[t]);
}

__global__ void k_bn_finalize(const float* __restrict__ sums,
                              const float* __restrict__ gamma, const float* __restrict__ beta,
                              const float* __restrict__ We1, const float* __restrict__ ae1,
                              const float* __restrict__ We2, const float* __restrict__ ae2,
                              const float* __restrict__ We3, const float* __restrict__ ae3,
                              float* __restrict__ misc, int n){
  int t = threadIdx.x;
  if (t < D){
    float mean = sums[t] / (float)n;
    float var  = sums[D + t] / (float)n - mean * mean;
    float inv  = rsqrtf(var + 1e-5f);
    float sc = gamma[t] * inv;
    misc[t] = sc;
    misc[D + t] = beta[t] - mean * sc;
  } else if (t == D){
    float c = 0.f; for (int d = 0; d < D; d++) c += We1[d] * ae1[d]; misc[2*D + 0] = c;
  } else if (t == D + 1){
    float c = 0.f; for (int d = 0; d < D; d++) c += We2[d] * ae2[d]; misc[2*D + 1] = c;
  } else if (t == D + 2){
    float c = 0.f; for (int d = 0; d < D; d++) c += We3[d] * ae3[d]; misc[2*D + 2] = c;
  }
}

// ---------------- CSR build: binned counting sort ----------------
// pass 0: bucket (dst>>8) histogram
__global__ __launch_bounds__(256) void k_hist(const int* __restrict__ dst,
                                              int* __restrict__ bhist, int E){
  __shared__ int h[256];
  int t = threadIdx.x;
  h[t] = 0;
  __syncthreads();
  int stride = gridDim.x * blockDim.x;
  for (int e = blockIdx.x * blockDim.x + t; e < E; e += stride)
    atomicAdd(&h[dst[e] >> 8], 1);
  __syncthreads();
  if (h[t]) atomicAdd(&bhist[t], h[t]);
}

// scan bucket counts -> bases + init global cursors; also rowptr[N]=E
__global__ void k_bscan(const int* __restrict__ bhist, int* __restrict__ bbase,
                        int* __restrict__ gcur, int* __restrict__ rowptr, int N, int E){
  __shared__ int sh[256];
  int t = threadIdx.x;
  int v = bhist[t];
  sh[t] = v; __syncthreads();
  for (int o = 1; o < 256; o <<= 1){
    int u = (t >= o) ? sh[t - o] : 0;
    __syncthreads();
    sh[t] += u;
    __syncthreads();
  }
  int ex = sh[t] - v;
  bbase[t] = ex;
  gcur[t] = ex;
  if (t == 255){ bbase[256] = sh[255]; rowptr[N] = E; }
}

// pass 1: partition edges into bucket-contiguous tmp, LDS-staged cursors
#define PCHUNK 4096
__global__ __launch_bounds__(256) void k_part(const int* __restrict__ src, const int* __restrict__ dst,
                                              const float* __restrict__ ew,
                                              int* __restrict__ gcur, int2* __restrict__ tmp, int E){
  __shared__ int hist[256];
  __shared__ int base[256];
  int t = threadIdx.x;
  int e0 = blockIdx.x * PCHUNK;
  int eend = min(E, e0 + PCHUNK);
  hist[t] = 0;
  __syncthreads();
  for (int e = e0 + t; e < eend; e += 256)
    atomicAdd(&hist[dst[e] >> 8], 1);
  __syncthreads();
  if (hist[t] > 0) base[t] = atomicAdd(&gcur[t], hist[t]);
  hist[t] = 0;   // reuse as local cursor
  __syncthreads();
  for (int e = e0 + t; e < eend; e += 256){
    int d = dst[e];
    int b = d >> 8;
    int off = atomicAdd(&hist[b], 1);
    // pack: src (16b, N<65536) | dst-low (8b) << 16 ; ew bits
    tmp[base[b] + off] = make_int2((src[e] & 0xffff) | ((d & 255) << 16), __float_as_int(ew[e]));
  }
}

// pass 2: per-bucket sort by dst-low -> final epair + rowptr
__global__ __launch_bounds__(256) void k_bsort(const int2* __restrict__ tmp, const int* __restrict__ bbase,
                                               int2* __restrict__ epair, int* __restrict__ rowptr, int N){
  __shared__ int2 ebuf[CAP];
  __shared__ int lcnt[256];
  __shared__ int sc[256];
  __shared__ int lcur[256];
  int b = blockIdx.x, t = threadIdx.x;
  int s0 = bbase[b], s1 = bbase[b + 1];
  int cnt = s1 - s0;
  lcnt[t] = 0;
  __syncthreads();
  for (int j = t; j < cnt; j += 256){
    int2 e = tmp[s0 + j];
    if (j < CAP) ebuf[j] = e;
    atomicAdd(&lcnt[(e.x >> 16) & 255], 1);
  }
  __syncthreads();
  int v = lcnt[t];
  sc[t] = v; __syncthreads();
  for (int o = 1; o < 256; o <<= 1){
    int u = (t >= o) ? sc[t - o] : 0;
    __syncthreads();
    sc[t] += u;
    __syncthreads();
  }
  int ex = sc[t] - v;
  int node = (b << 8) + t;
  if (node < N) rowptr[node] = s0 + ex;
  lcur[t] = ex;
  __syncthreads();
  for (int j = t; j < cnt; j += 256){
    int2 e = (j < CAP) ? ebuf[j] : tmp[s0 + j];
    int i = (e.x >> 16) & 255;
    int p = atomicAdd(&lcur[i], 1);
    epair[s0 + p] = make_int2(e.x & 0xffff, e.y);
  }
}

// ---------------- GAT GEMM: y = x@W (raw) + att dots; optional fused BN on input ----------------
template<bool BN_IN>
__global__ __launch_bounds__(256) void k_gemm(const float* __restrict__ xin, int in_stride,
                                              const float* __restrict__ W,
                                              const float* __restrict__ att_s, const float* __restrict__ att_d,
                                              const float* __restrict__ bn_misc,
                                              float* __restrict__ out,
                                              float* __restrict__ a_src, float* __restrict__ a_dst, int n){
  constexpr int CQ = 17, RG = 15;
  constexpr int NT  = CQ * RG;          // 255
  constexpr int RB  = RG * 4;           // 60
  constexpr int CQ4 = CQ * 4;           // 68
  __shared__ float xs[RB * SP];
  __shared__ float Ws[SP * CQ4];
  const int t = threadIdx.x;
  const int row0 = blockIdx.x * RB;

  if (t < NT){
    for (int f = t; f < SP * CQ4; f += NT){
      int k = f / CQ4, c = f % CQ4;
      Ws[f] = (k < D && c < D) ? W[k * D + c] : 0.f;
    }
    if (BN_IN){
      for (int f = t; f < RB * (SP/2); f += NT){
        int r = f / (SP/2), c = 2 * (f % (SP/2));
        float2 v = make_float2(0.f, 0.f);
        if (row0 + r < n && c < D){
          float2 hv = *(const float2*)&xin[(size_t)(row0 + r) * in_stride + c];
          v.x = hv.x * bn_misc[c]     + bn_misc[D + c];
          v.y = hv.y * bn_misc[c + 1] + bn_misc[D + c + 1];
        }
        *(float2*)&xs[r * SP + c] = v;
      }
    } else {
      for (int f = t; f < RB * (SP/4); f += NT){
        int r = f / (SP/4), q = f % (SP/4);
        float4 v = make_float4(0.f, 0.f, 0.f, 0.f);
        if (row0 + r < n) v = *(const float4*)&xin[(size_t)(row0 + r) * in_stride + 4 * q];
        *(float4*)&xs[r * SP + 4 * q] = v;
      }
    }
  }
  __syncthreads();

  const int ry = t / CQ, cq = t % CQ;
  float4 acc[4];
  #pragma unroll
  for (int i = 0; i < 4; i++) acc[i] = make_float4(0.f, 0.f, 0.f, 0.f);

  if (t < NT){
    for (int kc = 0; kc < SP / 4; kc++){
      int k0 = kc * 4;
      float4 w0 = *(const float4*)&Ws[(k0 + 0) * CQ4 + 4 * cq];
      float4 w1 = *(const float4*)&Ws[(k0 + 1) * CQ4 + 4 * cq];
      float4 w2 = *(const float4*)&Ws[(k0 + 2) * CQ4 + 4 * cq];
      float4 w3 = *(const float4*)&Ws[(k0 + 3) * CQ4 + 4 * cq];
      #pragma unroll
      for (int i = 0; i < 4; i++){
        float4 xv = *(const float4*)&xs[(ry * 4 + i) * SP + k0];
        fma4(acc[i], xv.x, w0);
        fma4(acc[i], xv.y, w1);
        fma4(acc[i], xv.z, w2);
        fma4(acc[i], xv.w, w3);
      }
    }
  }

  float ps[4] = {0.f,0.f,0.f,0.f}, pd[4] = {0.f,0.f,0.f,0.f};
  if (t < NT){
    #pragma unroll
    for (int i = 0; i < 4; i++){
      int row = row0 + ry * 4 + i;
      if (row >= n) continue;
      const float* ai = (const float*)&acc[i];
      float4 v; float* vp = (float*)&v;
      #pragma unroll
      for (int j = 0; j < 4; j++){
        int c = 4 * cq + j;
        float o = 0.f;
        if (c < D){
          float a = ai[j];
          ps[i] += a * att_s[c];
          pd[i] += a * att_d[c];
          o = a;
        }
        vp[j] = o;
      }
      *(float4*)&out[(size_t)row * SP + 4 * cq] = v;
    }
  }

  __syncthreads();                 // reuse xs for att partials
  float* pss = xs;
  float* psd = xs + RB * CQ;
  if (t < NT){
    #pragma unroll
    for (int i = 0; i < 4; i++){
      pss[(ry * 4 + i) * CQ + cq] = ps[i];
      psd[(ry * 4 + i) * CQ + cq] = pd[i];
    }
  }
  __syncthreads();
  for (int r = t; r < RB; r += blockDim.x){
    if (row0 + r < n){
      float s = 0.f, d2 = 0.f;
      for (int q = 0; q < CQ; q++){ s += pss[r * CQ + q]; d2 += psd[r * CQ + q]; }
      a_src[row0 + r] = s;
      a_dst[row0 + r] = d2;
    }
  }
}

// ---------------- Fused 5-layer FC head ----------------
__global__ __launch_bounds__(256) void k_fc(const float* __restrict__ xin,
                                            const float* __restrict__ W1, const float* __restrict__ B1,
                                            const float* __restrict__ W2, const float* __restrict__ B2,
                                            const float* __restrict__ W3, const float* __restrict__ B3,
                                            const float* __restrict__ W4, const float* __restrict__ B4,
                                            const float* __restrict__ W5, const float* __restrict__ B5,
                                            float* __restrict__ out, int n){
  constexpr int CQ = 17, RG = 15;
  constexpr int NT  = CQ * RG;          // 255
  constexpr int RB  = RG * 4;           // 60
  constexpr int CQ4 = CQ * 4;           // 68
  __shared__ float xs0[RB * SP];
  __shared__ float xs1[RB * SP];
  __shared__ float Ws[SP * CQ4];
  __shared__ float bs[CQ4];
  const int t = threadIdx.x;
  const int row0 = blockIdx.x * RB;
  const float* Wl[5] = {W1, W2, W3, W4, W5};
  const float* Bl[5] = {B1, B2, B3, B4, B5};

  // stage input tile
  for (int f = t; f < RB * (SP/4); f += 256){
    int r = f / (SP/4), q = f % (SP/4);
    float4 v = make_float4(0.f, 0.f, 0.f, 0.f);
    if (row0 + r < n) v = *(const float4*)&xin[(size_t)(row0 + r) * SP + 4 * q];
    *(float4*)&xs0[r * SP + 4 * q] = v;
  }

  const int ry = t / CQ, cq = t % CQ;
  float* xi = xs0;
  float* xo = xs1;

  for (int l = 0; l < 5; l++){
    const int ncol = (l == 4) ? 22 : D;
    __syncthreads();   // prior compute done (Ws consumers / xo readers finished)
    for (int f = t; f < SP * CQ4; f += 256){
      int k = f / CQ4, c = f % CQ4;
      Ws[f] = (k < D && c < ncol) ? Wl[l][k * ncol + c] : 0.f;
    }
    if (t < CQ4) bs[t] = (t < ncol) ? Bl[l][t] : 0.f;
    __syncthreads();   // Ws ready, xi ready

    float4 acc[4];
    #pragma unroll
    for (int i = 0; i < 4; i++) acc[i] = make_float4(0.f, 0.f, 0.f, 0.f);
    if (t < NT && (l < 4 || cq < 6)){
      for (int kc = 0; kc < SP / 4; kc++){
        int k0 = kc * 4;
        float4 w0 = *(const float4*)&Ws[(k0 + 0) * CQ4 + 4 * cq];
        float4 w1 = *(const float4*)&Ws[(k0 + 1) * CQ4 + 4 * cq];
        float4 w2 = *(const float4*)&Ws[(k0 + 2) * CQ4 + 4 * cq];
        float4 w3 = *(const float4*)&Ws[(k0 + 3) * CQ4 + 4 * cq];
        #pragma unroll
        for (int i = 0; i < 4; i++){
          float4 xv = *(const float4*)&xi[(ry * 4 + i) * SP + k0];
          fma4(acc[i], xv.x, w0);
          fma4(acc[i], xv.y, w1);
          fma4(acc[i], xv.z, w2);
          fma4(acc[i], xv.w, w3);
        }
      }
      if (l < 4){
        #pragma unroll
        for (int i = 0; i < 4; i++){
          float4 v; float* vp = (float*)&v;
          const float* ai = (const float*)&acc[i];
          #pragma unroll
          for (int j = 0; j < 4; j++){
            int c = 4 * cq + j;
            float a = (c < D) ? (ai[j] + bs[c]) : 0.f;
            vp[j] = a > 0.f ? a : 0.f;
          }
          *(float4*)&xo[(ry * 4 + i) * SP + 4 * cq] = v;
        }
      } else {
        #pragma unroll
        for (int i = 0; i < 4; i++){
          int row = row0 + ry * 4 + i;
          if (row >= n) continue;
          const float* ai = (const float*)&acc[i];
          #pragma unroll
          for (int j = 0; j < 4; j++){
            int c = 4 * cq + j;
            if (c < 22) out[(size_t)row * 22 + c] = ai[j] + bs[c];
          }
        }
      }
    }
    float* tmp = xi; xi = xo; xo = tmp;
  }
}

// ---------------- GAT softmax + aggregate: one wave per dst node ----------------
__global__ __launch_bounds__(256) void k_agg(const float* __restrict__ y,
                                             const float* __restrict__ a_src, const float* __restrict__ a_dst,
                                             const int* __restrict__ rowptr, const int2* __restrict__ epair,
                                             const float* __restrict__ misc, int cidx,
                                             const float* __restrict__ bias,
                                             float* __restrict__ xout, int n){
  const int wid  = (int)((blockIdx.x * (size_t)blockDim.x + threadIdx.x) >> 6);
  const int lane = threadIdx.x & 63;
  if (wid >= n) return;
  const int beg = rowptr[wid];
  const int deg = rowptr[wid + 1] - beg;
  const float ce  = misc[2 * D + cidx];
  const float adn = a_dst[wid];
  const int g = lane >> 4, q = lane & 15;

  float4 vacc = make_float4(0.f, 0.f, 0.f, 0.f);
  float2 tacc = make_float2(0.f, 0.f);

  if (deg <= 64){
    int s = 0; float al = -INFINITY;
    bool act = lane < deg;
    if (act){
      int2 ep = epair[beg + lane];
      s = ep.x;
      al = lrelu(a_src[s] + adn + ce * __int_as_float(ep.y));
    }
    float m = al;
    #pragma unroll
    for (int o = 32; o; o >>= 1) m = fmaxf(m, __shfl_xor(m, o));
    float ex = act ? __expf(al - m) : 0.f;
    float sum = ex;
    #pragma unroll
    for (int o = 32; o; o >>= 1) sum += __shfl_xor(sum, o);
    float coef = ex * (1.f / (sum + 1e-16f));
    for (int e0 = 0; e0 < deg; e0 += 4){
      int e = e0 + g;
      int   st = __shfl(s, e);
      float ct = __shfl(coef, e);
      const float* row = y + (size_t)st * SP;
      float4 yv = *(const float4*)&row[4 * q];
      fma4(vacc, ct, yv);
      if (q == 0){
        float2 tv = *(const float2*)&row[64];
        tacc.x += ct * tv.x; tacc.y += ct * tv.y;
      }
    }
  } else {
    float m = -INFINITY;
    for (int j0 = 0; j0 < deg; j0 += 64){
      int j = j0 + lane;
      if (j < deg){
        int2 ep = epair[beg + j];
        m = fmaxf(m, lrelu(a_src[ep.x] + adn + ce * __int_as_float(ep.y)));
      }
    }
    #pragma unroll
    for (int o = 32; o; o >>= 1) m = fmaxf(m, __shfl_xor(m, o));
    float sum = 0.f;
    for (int j0 = 0; j0 < deg; j0 += 64){
      int j = j0 + lane;
      if (j < deg){
        int2 ep = epair[beg + j];
        sum += __expf(lrelu(a_src[ep.x] + adn + ce * __int_as_float(ep.y)) - m);
      }
    }
    #pragma unroll
    for (int o = 32; o; o >>= 1) sum += __shfl_xor(sum, o);
    float inv = 1.f / (sum + 1e-16f);
    for (int j0 = 0; j0 < deg; j0 += 64){
      int cnt = min(64, deg - j0);
      int s = 0; float coef = 0.f;
      if (lane < cnt){
        int2 ep = epair[beg + j0 + lane];
        s = ep.x;
        coef = __expf(lrelu(a_src[s] + adn + ce * __int_as_float(ep.y)) - m) * inv;
      }
      for (int e0 = 0; e0 < cnt; e0 += 4){
        int e = e0 + g;
        int   st = __shfl(s, e);
        float ct = __shfl(coef, e);
        const float* row = y + (size_t)st * SP;
        float4 yv = *(const float4*)&row[4 * q];
        fma4(vacc, ct, yv);
        if (q == 0){
          float2 tv = *(const float2*)&row[64];
          tacc.x += ct * tv.x; tacc.y += ct * tv.y;
        }
      }
    }
  }

  #pragma unroll
  for (int o = 16; o <= 32; o <<= 1){
    vacc.x += __shfl_xor(vacc.x, o);
    vacc.y += __shfl_xor(vacc.y, o);
    vacc.z += __shfl_xor(vacc.z, o);
    vacc.w += __shfl_xor(vacc.w, o);
    tacc.x += __shfl_xor(tacc.x, o);
    tacc.y += __shfl_xor(tacc.y, o);
  }
  float* orow = xout + (size_t)wid * SP;
  if (lane < 16){
    float4 v;
    v.x = vacc.x + bias[4*lane+0]; v.x = v.x > 0.f ? v.x : 0.f;
    v.y = vacc.y + bias[4*lane+1]; v.y = v.y > 0.f ? v.y : 0.f;
    v.z = vacc.z + bias[4*lane+2]; v.z = v.z > 0.f ? v.z : 0.f;
    v.w = vacc.w + bias[4*lane+3]; v.w = v.w > 0.f ? v.w : 0.f;
    *(float4*)&orow[4 * lane] = v;
  }
  if (lane == 0){
    float4 tv;
    tv.x = tacc.x + bias[64]; tv.x = tv.x > 0.f ? tv.x : 0.f;
    tv.y = tacc.y + bias[65]; tv.y = tv.y > 0.f ? tv.y : 0.f;
    tv.z = 0.f; tv.w = 0.f;
    *(float4*)&orow[64] = tv;
  }
}

// ---------------- launch ----------------
extern "C" void kernel_launch(void* const* d_in, const int* in_sizes, int n_in,
                              void* d_out, int out_size, void* d_ws, size_t ws_size,
                              hipStream_t stream){
  const float* h     = (const float*)d_in[0];
  const int*   ei    = (const int*)  d_in[1];
  const float* ew    = (const float*)d_in[2];
  const float* gamma = (const float*)d_in[3];
  const float* beta  = (const float*)d_in[4];
  const float *Wl[3], *bl[3], *asl[3], *adl[3], *Wel[3], *ael[3];
  int idx = 5;
  for (int l = 0; l < 3; l++){
    Wl[l]  = (const float*)d_in[idx++];
    bl[l]  = (const float*)d_in[idx++];
    asl[l] = (const float*)d_in[idx++];
    adl[l] = (const float*)d_in[idx++];
    Wel[l] = (const float*)d_in[idx++];
    ael[l] = (const float*)d_in[idx++];
  }
  const float *fw[5], *fb[5];
  for (int l = 0; l < 5; l++){ fw[l] = (const float*)d_in[idx++]; fb[l] = (const float*)d_in[idx++]; }

  int N = in_sizes[0] / D;
  int E = in_sizes[1] / 2;
  const int* src  = ei;
  const int* dstp = ei + E;

  char* base = (char*)d_ws;
  size_t o = 0;
  auto alloc = [&](size_t b){ size_t r = o; o += (b + 255) & ~(size_t)255; return r; };
  float* bufA   = (float*)(base + alloc((size_t)N * SP * 4));
  float* bufB   = (float*)(base + alloc((size_t)N * SP * 4));
  float* a_src  = (float*)(base + alloc((size_t)N * 4));
  float* a_dst  = (float*)(base + alloc((size_t)N * 4));
  float* misc   = (float*)(base + alloc(512 * 4));
  float* sums   = (float*)(base + alloc(2 * D * 4));
  int*   rowptr = (int*)  (base + alloc((size_t)(N + 1) * 4));
  int*   bhist  = (int*)  (base + alloc(256 * 4));
  int*   bbase  = (int*)  (base + alloc(257 * 4));
  int*   gcur   = (int*)  (base + alloc(256 * 4));
  int2*  epair  = (int2*) (base + alloc((size_t)E * 8));
  int2*  tmp    = (int2*)bufB;   // alias: bufB unused until first GEMM

  hipMemsetAsync(sums, 0, 2 * D * 4, stream);
  hipMemsetAsync(bhist, 0, 256 * 4, stream);

  k_bn_stats<<<256, 256, 0, stream>>>(h, sums, N);
  k_bn_finalize<<<1, 128, 0, stream>>>(sums, gamma, beta, Wel[0], ael[0], Wel[1], ael[1], Wel[2], ael[2], misc, N);

  int NB = (N + 255) >> 8;
  k_hist<<<256, 256, 0, stream>>>(dstp, bhist, E);
  k_bscan<<<1, 256, 0, stream>>>(bhist, bbase, gcur, rowptr, N, E);
  k_part<<<(E + PCHUNK - 1) / PCHUNK, 256, 0, stream>>>(src, dstp, ew, gcur, tmp, E);
  k_bsort<<<NB, 256, 0, stream>>>(tmp, bbase, epair, rowptr, N);

  constexpr int RB17 = 60;
  int gb = (N + RB17 - 1) / RB17;
  int ab = (N + 3) / 4;       // one wave per node

  k_gemm<true ><<<gb, 256, 0, stream>>>(h,    D,  Wl[0], asl[0], adl[0], misc, bufB, a_src, a_dst, N);
  k_agg<<<ab, 256, 0, stream>>>(bufB, a_src, a_dst, rowptr, epair, misc, 0, bl[0], bufA, N);
  k_gemm<false><<<gb, 256, 0, stream>>>(bufA, SP, Wl[1], asl[1], adl[1], misc, bufB, a_src, a_dst, N);
  k_agg<<<ab, 256, 0, stream>>>(bufB, a_src, a_dst, rowptr, epair, misc, 1, bl[1], bufA, N);
  k_gemm<false><<<gb, 256, 0, stream>>>(bufA, SP, Wl[2], asl[2], adl[2], misc, bufB, a_src, a_dst, N);
  k_agg<<<ab, 256, 0, stream>>>(bufB, a_src, a_dst, rowptr, epair, misc, 2, bl[2], bufA, N);

  k_fc<<<gb, 256, 0, stream>>>(bufA, fw[0], fb[0], fw[1], fb[1], fw[2], fb[2],
                               fw[3], fb[3], fw[4], fb[4], (float*)d_out, N);
}

// Round 7
// 512.777 us; speedup vs baseline: 1.5033x; 1.0089x over previous
//
#include <hip/hip_runtime.h>
#include <math.h>

#define D 66
#define SP 68                 // padded fp32 row stride, 16B-aligned rows, cols 66,67 always 0
#define NEG_SLOPE 0.2f
#define CAP 6144

typedef short s8v __attribute__((ext_vector_type(8)));   // 8 bf16 bit-patterns = 4 VGPRs
typedef float f4v __attribute__((ext_vector_type(4)));

__device__ __forceinline__ float lrelu(float a){ return a > 0.f ? a : NEG_SLOPE * a; }
__device__ __forceinline__ void fma4(float4& a, float s, const float4& w){
  a.x = fmaf(s, w.x, a.x); a.y = fmaf(s, w.y, a.y);
  a.z = fmaf(s, w.z, a.z); a.w = fmaf(s, w.w, a.w);
}
__device__ __forceinline__ unsigned short bf16r(float f){   // RNE f32->bf16
  unsigned u = __float_as_uint(f);
  u += 0x7FFFu + ((u >> 16) & 1u);
  return (unsigned short)(u >> 16);
}
__device__ __forceinline__ float bf16f(unsigned short b){
  return __uint_as_float(((unsigned)b) << 16);
}
// 3-term bf16 split: v = a0 + a1 + a2 (+ O(2^-27 |v|))
__device__ __forceinline__ void split8(const float* p, s8v& a0, s8v& a1, s8v& a2){
  #pragma unroll
  for (int j = 0; j < 8; j++){
    float v = p[j];
    unsigned short b0 = bf16r(v);  float f0 = bf16f(b0);
    float r1 = v - f0;
    unsigned short b1 = bf16r(r1); float f1 = bf16f(b1);
    unsigned short b2 = bf16r(r1 - f1);
    a0[j] = (short)b0; a1[j] = (short)b1; a2[j] = (short)b2;
  }
}
#define MM6(acc, a0, a1, a2, b0v, b1v, b2v)                                \
  acc = __builtin_amdgcn_mfma_f32_16x16x32_bf16(a0, b0v, acc, 0, 0, 0);    \
  acc = __builtin_amdgcn_mfma_f32_16x16x32_bf16(a1, b0v, acc, 0, 0, 0);    \
  acc = __builtin_amdgcn_mfma_f32_16x16x32_bf16(a0, b1v, acc, 0, 0, 0);    \
  acc = __builtin_amdgcn_mfma_f32_16x16x32_bf16(a2, b0v, acc, 0, 0, 0);    \
  acc = __builtin_amdgcn_mfma_f32_16x16x32_bf16(a1, b1v, acc, 0, 0, 0);    \
  acc = __builtin_amdgcn_mfma_f32_16x16x32_bf16(a0, b2v, acc, 0, 0, 0);

// ---------------- BatchNorm ----------------
__global__ __launch_bounds__(256) void k_bn_stats(const float* __restrict__ h,
                                                  float* __restrict__ sums, int n){
  __shared__ float ls[2 * D];
  int t = threadIdx.x;
  if (t < 2 * D) ls[t] = 0.f;
  __syncthreads();
  int rpb = (n + gridDim.x - 1) / gridDim.x;
  int r0 = blockIdx.x * rpb;
  int r1 = min(n, r0 + rpb);
  if (t < 3 * D){
    int c = t % D, seg = t / D;
    float s1 = 0.f, s2 = 0.f;
    for (int r = r0 + seg; r < r1; r += 3){
      float v = h[(size_t)r * D + c];
      s1 += v; s2 += v * v;
    }
    atomicAdd(&ls[c], s1);
    atomicAdd(&ls[D + c], s2);
  }
  __syncthreads();
  if (t < 2 * D) atomicAdd(&sums[t], ls[t]);
}

__global__ void k_bn_finalize(const float* __restrict__ sums,
                              const float* __restrict__ gamma, const float* __restrict__ beta,
                              const float* __restrict__ We1, const float* __restrict__ ae1,
                              const float* __restrict__ We2, const float* __restrict__ ae2,
                              const float* __restrict__ We3, const float* __restrict__ ae3,
                              float* __restrict__ misc, int n){
  int t = threadIdx.x;
  if (t < D){
    float mean = sums[t] / (float)n;
    float var  = sums[D + t] / (float)n - mean * mean;
    float inv  = rsqrtf(var + 1e-5f);
    float sc = gamma[t] * inv;
    misc[t] = sc;
    misc[D + t] = beta[t] - mean * sc;
  } else if (t == D){
    float c = 0.f; for (int d = 0; d < D; d++) c += We1[d] * ae1[d]; misc[2*D + 0] = c;
  } else if (t == D + 1){
    float c = 0.f; for (int d = 0; d < D; d++) c += We2[d] * ae2[d]; misc[2*D + 1] = c;
  } else if (t == D + 2){
    float c = 0.f; for (int d = 0; d < D; d++) c += We3[d] * ae3[d]; misc[2*D + 2] = c;
  }
}

// BN apply -> SP-padded fp32 (cols 66,67 = 0)
__global__ __launch_bounds__(256) void k_bn_apply(const float* __restrict__ h, const float* __restrict__ misc,
                                                  float* __restrict__ x, int n){
  int i = blockIdx.x * 256 + threadIdx.x;
  int r = i / (SP/2), c2 = i - r * (SP/2);
  if (r >= n) return;
  int c = 2 * c2;
  float2 v = make_float2(0.f, 0.f);
  if (c < D){
    float2 hv = *(const float2*)&h[(size_t)r * D + c];
    v.x = hv.x * misc[c]     + misc[D + c];
    v.y = hv.y * misc[c + 1] + misc[D + c + 1];
  }
  *(float2*)&x[(size_t)r * SP + c] = v;
}

// ---------------- GAT weight pre-pack into MFMA B-fragment layout (bf16 3-term) ----------------
__global__ __launch_bounds__(256) void k_pack(const float* __restrict__ w0, const float* __restrict__ w1,
                                              const float* __restrict__ w2,
                                              short* __restrict__ W0, short* __restrict__ W1,
                                              short* __restrict__ W2){
  int tid = blockIdx.x * 256 + threadIdx.x;
  if (tid >= 3 * 15 * 64) return;
  int L = tid & 63;
  int ct = (tid >> 6) % 15;
  int lay = tid / 960;
  const float* w = (lay == 0) ? w0 : ((lay == 1) ? w1 : w2);
  int c = ct / 5, t = ct % 5;
  int nn = t * 16 + (L & 15);
  int kb = c * 32 + (L >> 4) * 8;
  #pragma unroll
  for (int j = 0; j < 8; j++){
    int k = kb + j;
    float v = (k < D && nn < D) ? w[k * D + nn] : 0.f;
    unsigned short b0 = bf16r(v);  float f0 = bf16f(b0);
    float r1 = v - f0;
    unsigned short b1 = bf16r(r1); float f1 = bf16f(b1);
    unsigned short b2 = bf16r(r1 - f1);
    W0[tid * 8 + j] = (short)b0;
    W1[tid * 8 + j] = (short)b1;
    W2[tid * 8 + j] = (short)b2;
  }
}

// ---------------- CSR build: binned counting sort (round-3 verbatim) ----------------
__global__ __launch_bounds__(256) void k_hist(const int* __restrict__ dst,
                                              int* __restrict__ bhist, int E){
  __shared__ int h[256];
  int t = threadIdx.x;
  h[t] = 0;
  __syncthreads();
  int stride = gridDim.x * blockDim.x;
  for (int e = blockIdx.x * blockDim.x + t; e < E; e += stride)
    atomicAdd(&h[dst[e] >> 8], 1);
  __syncthreads();
  if (h[t]) atomicAdd(&bhist[t], h[t]);
}

__global__ void k_bscan(const int* __restrict__ bhist, int* __restrict__ bbase,
                        int* __restrict__ gcur, int* __restrict__ rowptr, int N, int E){
  __shared__ int sh[256];
  int t = threadIdx.x;
  int v = bhist[t];
  sh[t] = v; __syncthreads();
  for (int o = 1; o < 256; o <<= 1){
    int u = (t >= o) ? sh[t - o] : 0;
    __syncthreads();
    sh[t] += u;
    __syncthreads();
  }
  int ex = sh[t] - v;
  bbase[t] = ex;
  gcur[t] = ex;
  if (t == 255){ bbase[256] = sh[255]; rowptr[N] = E; }
}

#define PCHUNK 4096
__global__ __launch_bounds__(256) void k_part(const int* __restrict__ src, const int* __restrict__ dst,
                                              const float* __restrict__ ew,
                                              int* __restrict__ gcur, int2* __restrict__ tmp, int E){
  __shared__ int hist[256];
  __shared__ int base[256];
  int t = threadIdx.x;
  int e0 = blockIdx.x * PCHUNK;
  int eend = min(E, e0 + PCHUNK);
  hist[t] = 0;
  __syncthreads();
  for (int e = e0 + t; e < eend; e += 256)
    atomicAdd(&hist[dst[e] >> 8], 1);
  __syncthreads();
  if (hist[t] > 0) base[t] = atomicAdd(&gcur[t], hist[t]);
  hist[t] = 0;
  __syncthreads();
  for (int e = e0 + t; e < eend; e += 256){
    int d = dst[e];
    int b = d >> 8;
    int off = atomicAdd(&hist[b], 1);
    tmp[base[b] + off] = make_int2((src[e] & 0xffff) | ((d & 255) << 16), __float_as_int(ew[e]));
  }
}

__global__ __launch_bounds__(256) void k_bsort(const int2* __restrict__ tmp, const int* __restrict__ bbase,
                                               int2* __restrict__ epair, int* __restrict__ rowptr, int N){
  __shared__ int2 ebuf[CAP];
  __shared__ int lcnt[256];
  __shared__ int sc[256];
  __shared__ int lcur[256];
  int b = blockIdx.x, t = threadIdx.x;
  int s0 = bbase[b], s1 = bbase[b + 1];
  int cnt = s1 - s0;
  lcnt[t] = 0;
  __syncthreads();
  for (int j = t; j < cnt; j += 256){
    int2 e = tmp[s0 + j];
    if (j < CAP) ebuf[j] = e;
    atomicAdd(&lcnt[(e.x >> 16) & 255], 1);
  }
  __syncthreads();
  int v = lcnt[t];
  sc[t] = v; __syncthreads();
  for (int o = 1; o < 256; o <<= 1){
    int u = (t >= o) ? sc[t - o] : 0;
    __syncthreads();
    sc[t] += u;
    __syncthreads();
  }
  int ex = sc[t] - v;
  int node = (b << 8) + t;
  if (node < N) rowptr[node] = s0 + ex;
  lcur[t] = ex;
  __syncthreads();
  for (int j = t; j < cnt; j += 256){
    int2 e = (j < CAP) ? ebuf[j] : tmp[s0 + j];
    int i = (e.x >> 16) & 255;
    int p = atomicAdd(&lcur[i], 1);
    epair[s0 + p] = make_int2(e.x & 0xffff, e.y);
  }
}

// ---------------- GAT GEMM via 3-term bf16 MFMA: Y = X@W (+att dots), no LDS ----------------
__global__ __launch_bounds__(256) void k_mm(const float* __restrict__ X,
    const short* __restrict__ W0, const short* __restrict__ W1, const short* __restrict__ W2,
    const float* __restrict__ att_s, const float* __restrict__ att_d,
    float* __restrict__ Y, float* __restrict__ a_src, float* __restrict__ a_dst, int n){
  const int wv = threadIdx.x >> 6, L = threadIdx.x & 63;
  const int quad = L >> 4, m = L & 15;
  const int row0 = blockIdx.x * 64 + wv * 16;
  const int lrow = min(row0 + m, n - 1);
  const float* xr = X + (size_t)lrow * SP;
  f4v acc[5];
  #pragma unroll
  for (int t = 0; t < 5; t++) acc[t] = (f4v){0.f,0.f,0.f,0.f};

  #pragma unroll
  for (int c = 0; c < 3; c++){
    float xv[8];
    if (c < 2){
      float4 p0 = *(const float4*)&xr[c * 32 + quad * 8];
      float4 p1 = *(const float4*)&xr[c * 32 + quad * 8 + 4];
      xv[0] = p0.x; xv[1] = p0.y; xv[2] = p0.z; xv[3] = p0.w;
      xv[4] = p1.x; xv[5] = p1.y; xv[6] = p1.z; xv[7] = p1.w;
    } else {
      float4 p0 = make_float4(0.f, 0.f, 0.f, 0.f);
      if (quad == 0) p0 = *(const float4*)&xr[64];   // cols 64,65 real; 66,67 stored zeros
      xv[0] = p0.x; xv[1] = p0.y; xv[2] = p0.z; xv[3] = p0.w;
      xv[4] = 0.f; xv[5] = 0.f; xv[6] = 0.f; xv[7] = 0.f;
    }
    s8v a0, a1, a2;
    split8(xv, a0, a1, a2);
    const short* b0p = W0 + (c * 5) * 512 + L * 8;
    const short* b1p = W1 + (c * 5) * 512 + L * 8;
    const short* b2p = W2 + (c * 5) * 512 + L * 8;
    #pragma unroll
    for (int t = 0; t < 5; t++){
      s8v b0v = *(const s8v*)(b0p + t * 512);
      s8v b1v = *(const s8v*)(b1p + t * 512);
      s8v b2v = *(const s8v*)(b2p + t * 512);
      MM6(acc[t], a0, a1, a2, b0v, b1v, b2v)
    }
  }

  float ps[4] = {0.f,0.f,0.f,0.f}, pd[4] = {0.f,0.f,0.f,0.f};
  #pragma unroll
  for (int t = 0; t < 5; t++){
    int col = t * 16 + m;
    float as_v = 0.f, ad_v = 0.f;
    if (col < D){ as_v = att_s[col]; ad_v = att_d[col]; }
    #pragma unroll
    for (int r = 0; r < 4; r++){
      ps[r] += acc[t][r] * as_v;
      pd[r] += acc[t][r] * ad_v;
    }
  }
  #pragma unroll
  for (int r = 0; r < 4; r++){
    int rw = row0 + quad * 4 + r;
    if (rw < n){
      float* yr = Y + (size_t)rw * SP;
      #pragma unroll
      for (int t = 0; t < 4; t++) yr[t * 16 + m] = acc[t][r];
      if (m < 4) yr[64 + m] = (m < 2) ? acc[4][r] : 0.f;
    }
  }
  #pragma unroll
  for (int o = 1; o <= 8; o <<= 1){
    #pragma unroll
    for (int r = 0; r < 4; r++){
      ps[r] += __shfl_xor(ps[r], o);
      pd[r] += __shfl_xor(pd[r], o);
    }
  }
  if (m == 0){
    #pragma unroll
    for (int r = 0; r < 4; r++){
      int rw = row0 + quad * 4 + r;
      if (rw < n){ a_src[rw] = ps[r]; a_dst[rw] = pd[r]; }
    }
  }
}

// ---------------- Fused 5-layer FC head (round-3 vector version, verbatim) ----------------
__global__ __launch_bounds__(256) void k_fc(const float* __restrict__ xin,
                                            const float* __restrict__ W1, const float* __restrict__ B1,
                                            const float* __restrict__ W2, const float* __restrict__ B2,
                                            const float* __restrict__ W3, const float* __restrict__ B3,
                                            const float* __restrict__ W4, const float* __restrict__ B4,
                                            const float* __restrict__ W5, const float* __restrict__ B5,
                                            float* __restrict__ out, int n){
  constexpr int CQ = 17, RG = 15;
  constexpr int NT  = CQ * RG;          // 255
  constexpr int RB  = RG * 4;           // 60
  constexpr int CQ4 = CQ * 4;           // 68
  __shared__ float xs0[RB * SP];
  __shared__ float xs1[RB * SP];
  __shared__ float Ws[SP * CQ4];
  __shared__ float bs[CQ4];
  const int t = threadIdx.x;
  const int row0 = blockIdx.x * RB;
  const float* Wl[5] = {W1, W2, W3, W4, W5};
  const float* Bl[5] = {B1, B2, B3, B4, B5};

  for (int f = t; f < RB * (SP/4); f += 256){
    int r = f / (SP/4), q = f % (SP/4);
    float4 v = make_float4(0.f, 0.f, 0.f, 0.f);
    if (row0 + r < n) v = *(const float4*)&xin[(size_t)(row0 + r) * SP + 4 * q];
    *(float4*)&xs0[r * SP + 4 * q] = v;
  }

  const int ry = t / CQ, cq = t % CQ;
  float* xi = xs0;
  float* xo = xs1;

  for (int l = 0; l < 5; l++){
    const int ncol = (l == 4) ? 22 : D;
    __syncthreads();
    for (int f = t; f < SP * CQ4; f += 256){
      int k = f / CQ4, c = f % CQ4;
      Ws[f] = (k < D && c < ncol) ? Wl[l][k * ncol + c] : 0.f;
    }
    if (t < CQ4) bs[t] = (t < ncol) ? Bl[l][t] : 0.f;
    __syncthreads();

    float4 acc[4];
    #pragma unroll
    for (int i = 0; i < 4; i++) acc[i] = make_float4(0.f, 0.f, 0.f, 0.f);
    if (t < NT && (l < 4 || cq < 6)){
      for (int kc = 0; kc < SP / 4; kc++){
        int k0 = kc * 4;
        float4 w0 = *(const float4*)&Ws[(k0 + 0) * CQ4 + 4 * cq];
        float4 w1 = *(const float4*)&Ws[(k0 + 1) * CQ4 + 4 * cq];
        float4 w2 = *(const float4*)&Ws[(k0 + 2) * CQ4 + 4 * cq];
        float4 w3 = *(const float4*)&Ws[(k0 + 3) * CQ4 + 4 * cq];
        #pragma unroll
        for (int i = 0; i < 4; i++){
          float4 xv = *(const float4*)&xi[(ry * 4 + i) * SP + k0];
          fma4(acc[i], xv.x, w0);
          fma4(acc[i], xv.y, w1);
          fma4(acc[i], xv.z, w2);
          fma4(acc[i], xv.w, w3);
        }
      }
      if (l < 4){
        #pragma unroll
        for (int i = 0; i < 4; i++){
          float4 v; float* vp = (float*)&v;
          const float* ai = (const float*)&acc[i];
          #pragma unroll
          for (int j = 0; j < 4; j++){
            int c = 4 * cq + j;
            float a = (c < D) ? (ai[j] + bs[c]) : 0.f;
            vp[j] = a > 0.f ? a : 0.f;
          }
          *(float4*)&xo[(ry * 4 + i) * SP + 4 * cq] = v;
        }
      } else {
        #pragma unroll
        for (int i = 0; i < 4; i++){
          int row = row0 + ry * 4 + i;
          if (row >= n) continue;
          const float* ai = (const float*)&acc[i];
          #pragma unroll
          for (int j = 0; j < 4; j++){
            int c = 4 * cq + j;
            if (c < 22) out[(size_t)row * 22 + c] = ai[j] + bs[c];
          }
        }
      }
    }
    float* tmp = xi; xi = xo; xo = tmp;
  }
}

// ---------------- GAT softmax + aggregate (round-3 4-group version, verbatim) ----------------
__global__ __launch_bounds__(256) void k_agg(const float* __restrict__ y,
                                             const float* __restrict__ a_src, const float* __restrict__ a_dst,
                                             const int* __restrict__ rowptr, const int2* __restrict__ epair,
                                             const float* __restrict__ misc, int cidx,
                                             const float* __restrict__ bias,
                                             float* __restrict__ xout, int n){
  const int wid  = (int)((blockIdx.x * (size_t)blockDim.x + threadIdx.x) >> 6);
  const int lane = threadIdx.x & 63;
  if (wid >= n) return;
  const int beg = rowptr[wid];
  const int deg = rowptr[wid + 1] - beg;
  const float ce  = misc[2 * D + cidx];
  const float adn = a_dst[wid];
  const int g = lane >> 4, q = lane & 15;

  float4 vacc = make_float4(0.f, 0.f, 0.f, 0.f);
  float2 tacc = make_float2(0.f, 0.f);

  if (deg <= 64){
    int s = 0; float al = -INFINITY;
    bool act = lane < deg;
    if (act){
      int2 ep = epair[beg + lane];
      s = ep.x;
      al = lrelu(a_src[s] + adn + ce * __int_as_float(ep.y));
    }
    float m = al;
    #pragma unroll
    for (int o = 32; o; o >>= 1) m = fmaxf(m, __shfl_xor(m, o));
    float ex = act ? __expf(al - m) : 0.f;
    float sum = ex;
    #pragma unroll
    for (int o = 32; o; o >>= 1) sum += __shfl_xor(sum, o);
    float coef = ex * (1.f / (sum + 1e-16f));
    for (int e0 = 0; e0 < deg; e0 += 4){
      int e = e0 + g;
      int   st = __shfl(s, e);
      float ct = __shfl(coef, e);
      const float* row = y + (size_t)st * SP;
      float4 yv = *(const float4*)&row[4 * q];
      fma4(vacc, ct, yv);
      if (q == 0){
        float2 tv = *(const float2*)&row[64];
        tacc.x += ct * tv.x; tacc.y += ct * tv.y;
      }
    }
  } else {
    float m = -INFINITY;
    for (int j0 = 0; j0 < deg; j0 += 64){
      int j = j0 + lane;
      if (j < deg){
        int2 ep = epair[beg + j];
        m = fmaxf(m, lrelu(a_src[ep.x] + adn + ce * __int_as_float(ep.y)));
      }
    }
    #pragma unroll
    for (int o = 32; o; o >>= 1) m = fmaxf(m, __shfl_xor(m, o));
    float sum = 0.f;
    for (int j0 = 0; j0 < deg; j0 += 64){
      int j = j0 + lane;
      if (j < deg){
        int2 ep = epair[beg + j];
        sum += __expf(lrelu(a_src[ep.x] + adn + ce * __int_as_float(ep.y)) - m);
      }
    }
    #pragma unroll
    for (int o = 32; o; o >>= 1) sum += __shfl_xor(sum, o);
    float inv = 1.f / (sum + 1e-16f);
    for (int j0 = 0; j0 < deg; j0 += 64){
      int cnt = min(64, deg - j0);
      int s = 0; float coef = 0.f;
      if (lane < cnt){
        int2 ep = epair[beg + j0 + lane];
        s = ep.x;
        coef = __expf(lrelu(a_src[s] + adn + ce * __int_as_float(ep.y)) - m) * inv;
      }
      for (int e0 = 0; e0 < cnt; e0 += 4){
        int e = e0 + g;
        int   st = __shfl(s, e);
        float ct = __shfl(coef, e);
        const float* row = y + (size_t)st * SP;
        float4 yv = *(const float4*)&row[4 * q];
        fma4(vacc, ct, yv);
        if (q == 0){
          float2 tv = *(const float2*)&row[64];
          tacc.x += ct * tv.x; tacc.y += ct * tv.y;
        }
      }
    }
  }

  #pragma unroll
  for (int o = 16; o <= 32; o <<= 1){
    vacc.x += __shfl_xor(vacc.x, o);
    vacc.y += __shfl_xor(vacc.y, o);
    vacc.z += __shfl_xor(vacc.z, o);
    vacc.w += __shfl_xor(vacc.w, o);
    tacc.x += __shfl_xor(tacc.x, o);
    tacc.y += __shfl_xor(tacc.y, o);
  }
  float* orow = xout + (size_t)wid * SP;
  if (lane < 16){
    float4 v;
    v.x = vacc.x + bias[4*lane+0]; v.x = v.x > 0.f ? v.x : 0.f;
    v.y = vacc.y + bias[4*lane+1]; v.y = v.y > 0.f ? v.y : 0.f;
    v.z = vacc.z + bias[4*lane+2]; v.z = v.z > 0.f ? v.z : 0.f;
    v.w = vacc.w + bias[4*lane+3]; v.w = v.w > 0.f ? v.w : 0.f;
    *(float4*)&orow[4 * lane] = v;
  }
  if (lane == 0){
    float4 tv;
    tv.x = tacc.x + bias[64]; tv.x = tv.x > 0.f ? tv.x : 0.f;
    tv.y = tacc.y + bias[65]; tv.y = tv.y > 0.f ? tv.y : 0.f;
    tv.z = 0.f; tv.w = 0.f;
    *(float4*)&orow[64] = tv;
  }
}

// ---------------- launch ----------------
extern "C" void kernel_launch(void* const* d_in, const int* in_sizes, int n_in,
                              void* d_out, int out_size, void* d_ws, size_t ws_size,
                              hipStream_t stream){
  const float* h     = (const float*)d_in[0];
  const int*   ei    = (const int*)  d_in[1];
  const float* ew    = (const float*)d_in[2];
  const float* gamma = (const float*)d_in[3];
  const float* beta  = (const float*)d_in[4];
  const float *Wl[3], *bl[3], *asl[3], *adl[3], *Wel[3], *ael[3];
  int idx = 5;
  for (int l = 0; l < 3; l++){
    Wl[l]  = (const float*)d_in[idx++];
    bl[l]  = (const float*)d_in[idx++];
    asl[l] = (const float*)d_in[idx++];
    adl[l] = (const float*)d_in[idx++];
    Wel[l] = (const float*)d_in[idx++];
    ael[l] = (const float*)d_in[idx++];
  }
  const float *fw[5], *fb[5];
  for (int l = 0; l < 5; l++){ fw[l] = (const float*)d_in[idx++]; fb[l] = (const float*)d_in[idx++]; }

  int N = in_sizes[0] / D;
  int E = in_sizes[1] / 2;
  const int* src  = ei;
  const int* dstp = ei + E;

  char* base = (char*)d_ws;
  size_t o = 0;
  auto alloc = [&](size_t b){ size_t r = o; o += (b + 255) & ~(size_t)255; return r; };
  float*  bufA   = (float*)(base + alloc((size_t)N * SP * 4));
  float*  bufB   = (float*)(base + alloc((size_t)N * SP * 4));
  float*  a_src  = (float*)(base + alloc((size_t)N * 4));
  float*  a_dst  = (float*)(base + alloc((size_t)N * 4));
  float*  misc   = (float*)(base + alloc(512 * 4));
  float*  sums   = (float*)(base + alloc(2 * D * 4));
  int*    rowptr = (int*)  (base + alloc((size_t)(N + 1) * 4));
  int*    bhist  = (int*)  (base + alloc(256 * 4));
  int*    bbase  = (int*)  (base + alloc(257 * 4));
  int*    gcur   = (int*)  (base + alloc(256 * 4));
  int2*   epair  = (int2*) (base + alloc((size_t)E * 8));
  short*  W0p    = (short*)(base + alloc(3 * 7680 * 2));
  short*  W1p    = (short*)(base + alloc(3 * 7680 * 2));
  short*  W2p    = (short*)(base + alloc(3 * 7680 * 2));
  int2*   tmp    = (int2*)bufB;   // alias: bufB unused until first k_mm

  hipMemsetAsync(sums, 0, 2 * D * 4, stream);
  hipMemsetAsync(bhist, 0, 256 * 4, stream);

  k_bn_stats<<<256, 256, 0, stream>>>(h, sums, N);
  k_bn_finalize<<<1, 128, 0, stream>>>(sums, gamma, beta, Wel[0], ael[0], Wel[1], ael[1], Wel[2], ael[2], misc, N);
  k_pack<<<12, 256, 0, stream>>>(Wl[0], Wl[1], Wl[2], W0p, W1p, W2p);

  int NB = (N + 255) >> 8;
  k_hist<<<256, 256, 0, stream>>>(dstp, bhist, E);
  k_bscan<<<1, 256, 0, stream>>>(bhist, bbase, gcur, rowptr, N, E);
  k_part<<<(E + PCHUNK - 1) / PCHUNK, 256, 0, stream>>>(src, dstp, ew, gcur, tmp, E);
  k_bsort<<<NB, 256, 0, stream>>>(tmp, bbase, epair, rowptr, N);

  int bnb = ((size_t)N * (SP/2) + 255) / 256;
  k_bn_apply<<<bnb, 256, 0, stream>>>(h, misc, bufA, N);

  int gb = (N + 63) / 64;
  int ab = (N + 3) / 4;

  for (int l = 0; l < 3; l++){
    k_mm<<<gb, 256, 0, stream>>>(bufA, W0p + l * 7680, W1p + l * 7680, W2p + l * 7680,
                                 asl[l], adl[l], bufB, a_src, a_dst, N);
    k_agg<<<ab, 256, 0, stream>>>(bufB, a_src, a_dst, rowptr, epair, misc, l, bl[l], bufA, N);
  }
  constexpr int RB17 = 60;
  int gb3 = (N + RB17 - 1) / RB17;
  k_fc<<<gb3, 256, 0, stream>>>(bufA, fw[0], fb[0], fw[1], fb[1], fw[2], fb[2],
                                fw[3], fb[3], fw[4], fb[4], (float*)d_out, N);
}

// Round 8
// 490.345 us; speedup vs baseline: 1.5721x; 1.0457x over previous
//
#include <hip/hip_runtime.h>
#include <math.h>

#define D 66
#define SP 68                 // padded fp32 row stride, 16B-aligned rows, cols 66,67 always 0
#define NEG_SLOPE 0.2f
#define CAP 6144

typedef short s8v __attribute__((ext_vector_type(8)));   // 8 bf16 bit-patterns = 4 VGPRs
typedef float f4v __attribute__((ext_vector_type(4)));

__device__ __forceinline__ float lrelu(float a){ return a > 0.f ? a : NEG_SLOPE * a; }
__device__ __forceinline__ void fma4(float4& a, float s, const float4& w){
  a.x = fmaf(s, w.x, a.x); a.y = fmaf(s, w.y, a.y);
  a.z = fmaf(s, w.z, a.z); a.w = fmaf(s, w.w, a.w);
}
__device__ __forceinline__ unsigned short bf16r(float f){   // RNE f32->bf16
  unsigned u = __float_as_uint(f);
  u += 0x7FFFu + ((u >> 16) & 1u);
  return (unsigned short)(u >> 16);
}
__device__ __forceinline__ float bf16f(unsigned short b){
  return __uint_as_float(((unsigned)b) << 16);
}
// 3-term bf16 split: v = a0 + a1 + a2 (+ O(2^-27 |v|))
__device__ __forceinline__ void split8(const float* p, s8v& a0, s8v& a1, s8v& a2){
  #pragma unroll
  for (int j = 0; j < 8; j++){
    float v = p[j];
    unsigned short b0 = bf16r(v);  float f0 = bf16f(b0);
    float r1 = v - f0;
    unsigned short b1 = bf16r(r1); float f1 = bf16f(b1);
    unsigned short b2 = bf16r(r1 - f1);
    a0[j] = (short)b0; a1[j] = (short)b1; a2[j] = (short)b2;
  }
}
#define MM6(acc, a0, a1, a2, b0v, b1v, b2v)                                \
  acc = __builtin_amdgcn_mfma_f32_16x16x32_bf16(a0, b0v, acc, 0, 0, 0);    \
  acc = __builtin_amdgcn_mfma_f32_16x16x32_bf16(a1, b0v, acc, 0, 0, 0);    \
  acc = __builtin_amdgcn_mfma_f32_16x16x32_bf16(a0, b1v, acc, 0, 0, 0);    \
  acc = __builtin_amdgcn_mfma_f32_16x16x32_bf16(a2, b0v, acc, 0, 0, 0);    \
  acc = __builtin_amdgcn_mfma_f32_16x16x32_bf16(a1, b1v, acc, 0, 0, 0);    \
  acc = __builtin_amdgcn_mfma_f32_16x16x32_bf16(a0, b2v, acc, 0, 0, 0);

// ---------------- BatchNorm ----------------
__global__ __launch_bounds__(256) void k_bn_stats(const float* __restrict__ h,
                                                  float* __restrict__ sums, int n){
  __shared__ float ls[2 * D];
  int t = threadIdx.x;
  if (t < 2 * D) ls[t] = 0.f;
  __syncthreads();
  int rpb = (n + gridDim.x - 1) / gridDim.x;
  int r0 = blockIdx.x * rpb;
  int r1 = min(n, r0 + rpb);
  if (t < 3 * D){
    int c = t % D, seg = t / D;
    float s1 = 0.f, s2 = 0.f;
    for (int r = r0 + seg; r < r1; r += 3){
      float v = h[(size_t)r * D + c];
      s1 += v; s2 += v * v;
    }
    atomicAdd(&ls[c], s1);
    atomicAdd(&ls[D + c], s2);
  }
  __syncthreads();
  if (t < 2 * D) atomicAdd(&sums[t], ls[t]);
}

__global__ void k_bn_finalize(const float* __restrict__ sums,
                              const float* __restrict__ gamma, const float* __restrict__ beta,
                              const float* __restrict__ We1, const float* __restrict__ ae1,
                              const float* __restrict__ We2, const float* __restrict__ ae2,
                              const float* __restrict__ We3, const float* __restrict__ ae3,
                              float* __restrict__ misc, int n){
  int t = threadIdx.x;
  if (t < D){
    float mean = sums[t] / (float)n;
    float var  = sums[D + t] / (float)n - mean * mean;
    float inv  = rsqrtf(var + 1e-5f);
    float sc = gamma[t] * inv;
    misc[t] = sc;
    misc[D + t] = beta[t] - mean * sc;
  } else if (t == D){
    float c = 0.f; for (int d = 0; d < D; d++) c += We1[d] * ae1[d]; misc[2*D + 0] = c;
  } else if (t == D + 1){
    float c = 0.f; for (int d = 0; d < D; d++) c += We2[d] * ae2[d]; misc[2*D + 1] = c;
  } else if (t == D + 2){
    float c = 0.f; for (int d = 0; d < D; d++) c += We3[d] * ae3[d]; misc[2*D + 2] = c;
  }
}

// BN apply -> SP-padded fp32 (cols 66,67 = 0)
__global__ __launch_bounds__(256) void k_bn_apply(const float* __restrict__ h, const float* __restrict__ misc,
                                                  float* __restrict__ x, int n){
  int i = blockIdx.x * 256 + threadIdx.x;
  int r = i / (SP/2), c2 = i - r * (SP/2);
  if (r >= n) return;
  int c = 2 * c2;
  float2 v = make_float2(0.f, 0.f);
  if (c < D){
    float2 hv = *(const float2*)&h[(size_t)r * D + c];
    v.x = hv.x * misc[c]     + misc[D + c];
    v.y = hv.y * misc[c + 1] + misc[D + c + 1];
  }
  *(float2*)&x[(size_t)r * SP + c] = v;
}

// ---------------- GAT weight pre-pack into MFMA B-fragment layout (bf16 3-term) ----------------
__global__ __launch_bounds__(256) void k_pack(const float* __restrict__ w0, const float* __restrict__ w1,
                                              const float* __restrict__ w2,
                                              short* __restrict__ W0, short* __restrict__ W1,
                                              short* __restrict__ W2){
  int tid = blockIdx.x * 256 + threadIdx.x;
  if (tid >= 3 * 15 * 64) return;
  int L = tid & 63;
  int ct = (tid >> 6) % 15;
  int lay = tid / 960;
  const float* w = (lay == 0) ? w0 : ((lay == 1) ? w1 : w2);
  int c = ct / 5, t = ct % 5;
  int nn = t * 16 + (L & 15);
  int kb = c * 32 + (L >> 4) * 8;
  #pragma unroll
  for (int j = 0; j < 8; j++){
    int k = kb + j;
    float v = (k < D && nn < D) ? w[k * D + nn] : 0.f;
    unsigned short b0 = bf16r(v);  float f0 = bf16f(b0);
    float r1 = v - f0;
    unsigned short b1 = bf16r(r1); float f1 = bf16f(b1);
    unsigned short b2 = bf16r(r1 - f1);
    W0[tid * 8 + j] = (short)b0;
    W1[tid * 8 + j] = (short)b1;
    W2[tid * 8 + j] = (short)b2;
  }
}

// FC weight pre-pack (same layout; 5 layers, last has ncol=22)
__global__ __launch_bounds__(256) void k_packfc(const float* __restrict__ w0, const float* __restrict__ w1,
                                                const float* __restrict__ w2, const float* __restrict__ w3,
                                                const float* __restrict__ w4,
                                                short* __restrict__ W0, short* __restrict__ W1,
                                                short* __restrict__ W2){
  int tid = blockIdx.x * 256 + threadIdx.x;
  if (tid >= 5 * 15 * 64) return;
  int L = tid & 63;
  int ct = (tid >> 6) % 15;
  int lay = tid / 960;
  const float* w = (lay == 0) ? w0 : (lay == 1) ? w1 : (lay == 2) ? w2 : (lay == 3) ? w3 : w4;
  int ncol = (lay == 4) ? 22 : D;
  int c = ct / 5, t = ct % 5;
  int nn = t * 16 + (L & 15);
  int kb = c * 32 + (L >> 4) * 8;
  #pragma unroll
  for (int j = 0; j < 8; j++){
    int k = kb + j;
    float v = (k < D && nn < ncol) ? w[k * ncol + nn] : 0.f;
    unsigned short b0 = bf16r(v);  float f0 = bf16f(b0);
    float r1 = v - f0;
    unsigned short b1 = bf16r(r1); float f1 = bf16f(b1);
    unsigned short b2 = bf16r(r1 - f1);
    W0[tid * 8 + j] = (short)b0;
    W1[tid * 8 + j] = (short)b1;
    W2[tid * 8 + j] = (short)b2;
  }
}

// ---------------- CSR build: binned counting sort ----------------
__global__ __launch_bounds__(256) void k_hist(const int* __restrict__ dst,
                                              int* __restrict__ bhist, int E){
  __shared__ int h[256];
  int t = threadIdx.x;
  h[t] = 0;
  __syncthreads();
  int stride = gridDim.x * blockDim.x;
  for (int e = blockIdx.x * blockDim.x + t; e < E; e += stride)
    atomicAdd(&h[dst[e] >> 8], 1);
  __syncthreads();
  if (h[t]) atomicAdd(&bhist[t], h[t]);
}

__global__ void k_bscan(const int* __restrict__ bhist, int* __restrict__ bbase,
                        int* __restrict__ gcur, int* __restrict__ rowptr, int N, int E){
  __shared__ int sh[256];
  int t = threadIdx.x;
  int v = bhist[t];
  sh[t] = v; __syncthreads();
  for (int o = 1; o < 256; o <<= 1){
    int u = (t >= o) ? sh[t - o] : 0;
    __syncthreads();
    sh[t] += u;
    __syncthreads();
  }
  int ex = sh[t] - v;
  bbase[t] = ex;
  gcur[t] = ex;
  if (t == 255){ bbase[256] = sh[255]; rowptr[N] = E; }
}

#define PCHUNK 4096
__global__ __launch_bounds__(256) void k_part(const int* __restrict__ src, const int* __restrict__ dst,
                                              const float* __restrict__ ew,
                                              int* __restrict__ gcur, int2* __restrict__ tmp, int E){
  __shared__ int hist[256];
  __shared__ int base[256];
  int t = threadIdx.x;
  int e0 = blockIdx.x * PCHUNK;
  int eend = min(E, e0 + PCHUNK);
  hist[t] = 0;
  __syncthreads();
  for (int e = e0 + t; e < eend; e += 256)
    atomicAdd(&hist[dst[e] >> 8], 1);
  __syncthreads();
  if (hist[t] > 0) base[t] = atomicAdd(&gcur[t], hist[t]);
  hist[t] = 0;
  __syncthreads();
  for (int e = e0 + t; e < eend; e += 256){
    int d = dst[e];
    int b = d >> 8;
    int off = atomicAdd(&hist[b], 1);
    tmp[base[b] + off] = make_int2((src[e] & 0xffff) | ((d & 255) << 16), __float_as_int(ew[e]));
  }
}

__global__ __launch_bounds__(256) void k_bsort(const int2* __restrict__ tmp, const int* __restrict__ bbase,
                                               int2* __restrict__ epair, int* __restrict__ rowptr, int N){
  __shared__ int2 ebuf[CAP];
  __shared__ int lcnt[256];
  __shared__ int sc[256];
  __shared__ int lcur[256];
  int b = blockIdx.x, t = threadIdx.x;
  int s0 = bbase[b], s1 = bbase[b + 1];
  int cnt = s1 - s0;
  lcnt[t] = 0;
  __syncthreads();
  for (int j = t; j < cnt; j += 256){
    int2 e = tmp[s0 + j];
    if (j < CAP) ebuf[j] = e;
    atomicAdd(&lcnt[(e.x >> 16) & 255], 1);
  }
  __syncthreads();
  int v = lcnt[t];
  sc[t] = v; __syncthreads();
  for (int o = 1; o < 256; o <<= 1){
    int u = (t >= o) ? sc[t - o] : 0;
    __syncthreads();
    sc[t] += u;
    __syncthreads();
  }
  int ex = sc[t] - v;
  int node = (b << 8) + t;
  if (node < N) rowptr[node] = s0 + ex;
  lcur[t] = ex;
  __syncthreads();
  for (int j = t; j < cnt; j += 256){
    int2 e = (j < CAP) ? ebuf[j] : tmp[s0 + j];
    int i = (e.x >> 16) & 255;
    int p = atomicAdd(&lcur[i], 1);
    epair[s0 + p] = make_int2(e.x & 0xffff, e.y);
  }
}

// ---------------- GAT GEMM via 3-term bf16 MFMA: Y = X@W (+att dots), no LDS ----------------
__global__ __launch_bounds__(256) void k_mm(const float* __restrict__ X,
    const short* __restrict__ W0, const short* __restrict__ W1, const short* __restrict__ W2,
    const float* __restrict__ att_s, const float* __restrict__ att_d,
    float* __restrict__ Y, float* __restrict__ a_src, float* __restrict__ a_dst, int n){
  const int wv = threadIdx.x >> 6, L = threadIdx.x & 63;
  const int quad = L >> 4, m = L & 15;
  const int row0 = blockIdx.x * 64 + wv * 16;
  const int lrow = min(row0 + m, n - 1);
  const float* xr = X + (size_t)lrow * SP;
  f4v acc[5];
  #pragma unroll
  for (int t = 0; t < 5; t++) acc[t] = (f4v){0.f,0.f,0.f,0.f};

  #pragma unroll
  for (int c = 0; c < 3; c++){
    float xv[8];
    if (c < 2){
      float4 p0 = *(const float4*)&xr[c * 32 + quad * 8];
      float4 p1 = *(const float4*)&xr[c * 32 + quad * 8 + 4];
      xv[0] = p0.x; xv[1] = p0.y; xv[2] = p0.z; xv[3] = p0.w;
      xv[4] = p1.x; xv[5] = p1.y; xv[6] = p1.z; xv[7] = p1.w;
    } else {
      float4 p0 = make_float4(0.f, 0.f, 0.f, 0.f);
      if (quad == 0) p0 = *(const float4*)&xr[64];   // cols 64,65 real; 66,67 stored zeros
      xv[0] = p0.x; xv[1] = p0.y; xv[2] = p0.z; xv[3] = p0.w;
      xv[4] = 0.f; xv[5] = 0.f; xv[6] = 0.f; xv[7] = 0.f;
    }
    s8v a0, a1, a2;
    split8(xv, a0, a1, a2);
    const short* b0p = W0 + (c * 5) * 512 + L * 8;
    const short* b1p = W1 + (c * 5) * 512 + L * 8;
    const short* b2p = W2 + (c * 5) * 512 + L * 8;
    #pragma unroll
    for (int t = 0; t < 5; t++){
      s8v b0v = *(const s8v*)(b0p + t * 512);
      s8v b1v = *(const s8v*)(b1p + t * 512);
      s8v b2v = *(const s8v*)(b2p + t * 512);
      MM6(acc[t], a0, a1, a2, b0v, b1v, b2v)
    }
  }

  float ps[4] = {0.f,0.f,0.f,0.f}, pd[4] = {0.f,0.f,0.f,0.f};
  #pragma unroll
  for (int t = 0; t < 5; t++){
    int col = t * 16 + m;
    float as_v = 0.f, ad_v = 0.f;
    if (col < D){ as_v = att_s[col]; ad_v = att_d[col]; }
    #pragma unroll
    for (int r = 0; r < 4; r++){
      ps[r] += acc[t][r] * as_v;
      pd[r] += acc[t][r] * ad_v;
    }
  }
  #pragma unroll
  for (int r = 0; r < 4; r++){
    int rw = row0 + quad * 4 + r;
    if (rw < n){
      float* yr = Y + (size_t)rw * SP;
      #pragma unroll
      for (int t = 0; t < 4; t++) yr[t * 16 + m] = acc[t][r];
      if (m < 4) yr[64 + m] = (m < 2) ? acc[4][r] : 0.f;
    }
  }
  #pragma unroll
  for (int o = 1; o <= 8; o <<= 1){
    #pragma unroll
    for (int r = 0; r < 4; r++){
      ps[r] += __shfl_xor(ps[r], o);
      pd[r] += __shfl_xor(pd[r], o);
    }
  }
  if (m == 0){
    #pragma unroll
    for (int r = 0; r < 4; r++){
      int rw = row0 + quad * 4 + r;
      if (rw < n){ a_src[rw] = ps[r]; a_dst[rw] = pd[r]; }
    }
  }
}

// ---------------- FC layer via 3-term bf16 MFMA (clone of proven k_mm, FC epilogue) ----------------
template<bool LAST>
__global__ __launch_bounds__(256) void k_fcl(const float* __restrict__ X,
    const short* __restrict__ W0, const short* __restrict__ W1, const short* __restrict__ W2,
    const float* __restrict__ bias,
    float* __restrict__ Y, int n){
  const int wv = threadIdx.x >> 6, L = threadIdx.x & 63;
  const int quad = L >> 4, m = L & 15;
  const int row0 = blockIdx.x * 64 + wv * 16;
  const int lrow = min(row0 + m, n - 1);
  const float* xr = X + (size_t)lrow * SP;
  constexpr int NT = LAST ? 2 : 5;
  f4v acc[NT];
  #pragma unroll
  for (int t = 0; t < NT; t++) acc[t] = (f4v){0.f,0.f,0.f,0.f};

  #pragma unroll
  for (int c = 0; c < 3; c++){
    float xv[8];
    if (c < 2){
      float4 p0 = *(const float4*)&xr[c * 32 + quad * 8];
      float4 p1 = *(const float4*)&xr[c * 32 + quad * 8 + 4];
      xv[0] = p0.x; xv[1] = p0.y; xv[2] = p0.z; xv[3] = p0.w;
      xv[4] = p1.x; xv[5] = p1.y; xv[6] = p1.z; xv[7] = p1.w;
    } else {
      float4 p0 = make_float4(0.f, 0.f, 0.f, 0.f);
      if (quad == 0) p0 = *(const float4*)&xr[64];
      xv[0] = p0.x; xv[1] = p0.y; xv[2] = p0.z; xv[3] = p0.w;
      xv[4] = 0.f; xv[5] = 0.f; xv[6] = 0.f; xv[7] = 0.f;
    }
    s8v a0, a1, a2;
    split8(xv, a0, a1, a2);
    const short* b0p = W0 + (c * 5) * 512 + L * 8;
    const short* b1p = W1 + (c * 5) * 512 + L * 8;
    const short* b2p = W2 + (c * 5) * 512 + L * 8;
    #pragma unroll
    for (int t = 0; t < NT; t++){
      s8v b0v = *(const s8v*)(b0p + t * 512);
      s8v b1v = *(const s8v*)(b1p + t * 512);
      s8v b2v = *(const s8v*)(b2p + t * 512);
      MM6(acc[t], a0, a1, a2, b0v, b1v, b2v)
    }
  }

  if (!LAST){
    #pragma unroll
    for (int r = 0; r < 4; r++){
      int rw = row0 + quad * 4 + r;
      if (rw < n){
        float* yr = Y + (size_t)rw * SP;
        #pragma unroll
        for (int t = 0; t < 4; t++){
          int col = t * 16 + m;                    // col <= 63 < D: bias valid
          float v = acc[t][r] + bias[col];
          yr[col] = v > 0.f ? v : 0.f;
        }
        if (m < 4){
          float v = 0.f;
          if (m < 2){
            v = acc[4][r] + bias[64 + m];          // cols 64,65
            v = v > 0.f ? v : 0.f;
          }
          yr[64 + m] = v;                          // cols 66,67 stay 0
        }
      }
    }
  } else {
    #pragma unroll
    for (int t = 0; t < 2; t++){
      int col = t * 16 + m;
      #pragma unroll
      for (int r = 0; r < 4; r++){
        int rw = row0 + quad * 4 + r;
        if (col < 22 && rw < n) Y[(size_t)rw * 22 + col] = acc[t][r] + bias[col];
      }
    }
  }
}

// ---------------- GAT softmax + aggregate (proven 4-group version) ----------------
__global__ __launch_bounds__(256) void k_agg(const float* __restrict__ y,
                                             const float* __restrict__ a_src, const float* __restrict__ a_dst,
                                             const int* __restrict__ rowptr, const int2* __restrict__ epair,
                                             const float* __restrict__ misc, int cidx,
                                             const float* __restrict__ bias,
                                             float* __restrict__ xout, int n){
  const int wid  = (int)((blockIdx.x * (size_t)blockDim.x + threadIdx.x) >> 6);
  const int lane = threadIdx.x & 63;
  if (wid >= n) return;
  const int beg = rowptr[wid];
  const int deg = rowptr[wid + 1] - beg;
  const float ce  = misc[2 * D + cidx];
  const float adn = a_dst[wid];
  const int g = lane >> 4, q = lane & 15;

  float4 vacc = make_float4(0.f, 0.f, 0.f, 0.f);
  float2 tacc = make_float2(0.f, 0.f);

  if (deg <= 64){
    int s = 0; float al = -INFINITY;
    bool act = lane < deg;
    if (act){
      int2 ep = epair[beg + lane];
      s = ep.x;
      al = lrelu(a_src[s] + adn + ce * __int_as_float(ep.y));
    }
    float m = al;
    #pragma unroll
    for (int o = 32; o; o >>= 1) m = fmaxf(m, __shfl_xor(m, o));
    float ex = act ? __expf(al - m) : 0.f;
    float sum = ex;
    #pragma unroll
    for (int o = 32; o; o >>= 1) sum += __shfl_xor(sum, o);
    float coef = ex * (1.f / (sum + 1e-16f));
    for (int e0 = 0; e0 < deg; e0 += 4){
      int e = e0 + g;
      int   st = __shfl(s, e);
      float ct = __shfl(coef, e);
      const float* row = y + (size_t)st * SP;
      float4 yv = *(const float4*)&row[4 * q];
      fma4(vacc, ct, yv);
      if (q == 0){
        float2 tv = *(const float2*)&row[64];
        tacc.x += ct * tv.x; tacc.y += ct * tv.y;
      }
    }
  } else {
    float m = -INFINITY;
    for (int j0 = 0; j0 < deg; j0 += 64){
      int j = j0 + lane;
      if (j < deg){
        int2 ep = epair[beg + j];
        m = fmaxf(m, lrelu(a_src[ep.x] + adn + ce * __int_as_float(ep.y)));
      }
    }
    #pragma unroll
    for (int o = 32; o; o >>= 1) m = fmaxf(m, __shfl_xor(m, o));
    float sum = 0.f;
    for (int j0 = 0; j0 < deg; j0 += 64){
      int j = j0 + lane;
      if (j < deg){
        int2 ep = epair[beg + j];
        sum += __expf(lrelu(a_src[ep.x] + adn + ce * __int_as_float(ep.y)) - m);
      }
    }
    #pragma unroll
    for (int o = 32; o; o >>= 1) sum += __shfl_xor(sum, o);
    float inv = 1.f / (sum + 1e-16f);
    for (int j0 = 0; j0 < deg; j0 += 64){
      int cnt = min(64, deg - j0);
      int s = 0; float coef = 0.f;
      if (lane < cnt){
        int2 ep = epair[beg + j0 + lane];
        s = ep.x;
        coef = __expf(lrelu(a_src[s] + adn + ce * __int_as_float(ep.y)) - m) * inv;
      }
      for (int e0 = 0; e0 < cnt; e0 += 4){
        int e = e0 + g;
        int   st = __shfl(s, e);
        float ct = __shfl(coef, e);
        const float* row = y + (size_t)st * SP;
        float4 yv = *(const float4*)&row[4 * q];
        fma4(vacc, ct, yv);
        if (q == 0){
          float2 tv = *(const float2*)&row[64];
          tacc.x += ct * tv.x; tacc.y += ct * tv.y;
        }
      }
    }
  }

  #pragma unroll
  for (int o = 16; o <= 32; o <<= 1){
    vacc.x += __shfl_xor(vacc.x, o);
    vacc.y += __shfl_xor(vacc.y, o);
    vacc.z += __shfl_xor(vacc.z, o);
    vacc.w += __shfl_xor(vacc.w, o);
    tacc.x += __shfl_xor(tacc.x, o);
    tacc.y += __shfl_xor(tacc.y, o);
  }
  float* orow = xout + (size_t)wid * SP;
  if (lane < 16){
    float4 v;
    v.x = vacc.x + bias[4*lane+0]; v.x = v.x > 0.f ? v.x : 0.f;
    v.y = vacc.y + bias[4*lane+1]; v.y = v.y > 0.f ? v.y : 0.f;
    v.z = vacc.z + bias[4*lane+2]; v.z = v.z > 0.f ? v.z : 0.f;
    v.w = vacc.w + bias[4*lane+3]; v.w = v.w > 0.f ? v.w : 0.f;
    *(float4*)&orow[4 * lane] = v;
  }
  if (lane == 0){
    float4 tv;
    tv.x = tacc.x + bias[64]; tv.x = tv.x > 0.f ? tv.x : 0.f;
    tv.y = tacc.y + bias[65]; tv.y = tv.y > 0.f ? tv.y : 0.f;
    tv.z = 0.f; tv.w = 0.f;
    *(float4*)&orow[64] = tv;
  }
}

// ---------------- launch ----------------
extern "C" void kernel_launch(void* const* d_in, const int* in_sizes, int n_in,
                              void* d_out, int out_size, void* d_ws, size_t ws_size,
                              hipStream_t stream){
  const float* h     = (const float*)d_in[0];
  const int*   ei    = (const int*)  d_in[1];
  const float* ew    = (const float*)d_in[2];
  const float* gamma = (const float*)d_in[3];
  const float* beta  = (const float*)d_in[4];
  const float *Wl[3], *bl[3], *asl[3], *adl[3], *Wel[3], *ael[3];
  int idx = 5;
  for (int l = 0; l < 3; l++){
    Wl[l]  = (const float*)d_in[idx++];
    bl[l]  = (const float*)d_in[idx++];
    asl[l] = (const float*)d_in[idx++];
    adl[l] = (const float*)d_in[idx++];
    Wel[l] = (const float*)d_in[idx++];
    ael[l] = (const float*)d_in[idx++];
  }
  const float *fw[5], *fb[5];
  for (int l = 0; l < 5; l++){ fw[l] = (const float*)d_in[idx++]; fb[l] = (const float*)d_in[idx++]; }

  int N = in_sizes[0] / D;
  int E = in_sizes[1] / 2;
  const int* src  = ei;
  const int* dstp = ei + E;

  char* base = (char*)d_ws;
  size_t o = 0;
  auto alloc = [&](size_t b){ size_t r = o; o += (b + 255) & ~(size_t)255; return r; };
  float*  bufA   = (float*)(base + alloc((size_t)N * SP * 4));
  float*  bufB   = (float*)(base + alloc((size_t)N * SP * 4));
  float*  a_src  = (float*)(base + alloc((size_t)N * 4));
  float*  a_dst  = (float*)(base + alloc((size_t)N * 4));
  float*  misc   = (float*)(base + alloc(512 * 4));
  float*  sums   = (float*)(base + alloc(2 * D * 4));
  int*    rowptr = (int*)  (base + alloc((size_t)(N + 1) * 4));
  int*    bhist  = (int*)  (base + alloc(256 * 4));
  int*    bbase  = (int*)  (base + alloc(257 * 4));
  int*    gcur   = (int*)  (base + alloc(256 * 4));
  int2*   epair  = (int2*) (base + alloc((size_t)E * 8));
  short*  W0p    = (short*)(base + alloc(3 * 7680 * 2));
  short*  W1p    = (short*)(base + alloc(3 * 7680 * 2));
  short*  W2p    = (short*)(base + alloc(3 * 7680 * 2));
  short*  FW0p   = (short*)(base + alloc(5 * 7680 * 2));
  short*  FW1p   = (short*)(base + alloc(5 * 7680 * 2));
  short*  FW2p   = (short*)(base + alloc(5 * 7680 * 2));
  int2*   tmp    = (int2*)bufB;   // alias: bufB unused until first k_mm

  hipMemsetAsync(sums, 0, 2 * D * 4, stream);
  hipMemsetAsync(bhist, 0, 256 * 4, stream);

  k_bn_stats<<<256, 256, 0, stream>>>(h, sums, N);
  k_bn_finalize<<<1, 128, 0, stream>>>(sums, gamma, beta, Wel[0], ael[0], Wel[1], ael[1], Wel[2], ael[2], misc, N);
  k_pack<<<12, 256, 0, stream>>>(Wl[0], Wl[1], Wl[2], W0p, W1p, W2p);
  k_packfc<<<19, 256, 0, stream>>>(fw[0], fw[1], fw[2], fw[3], fw[4], FW0p, FW1p, FW2p);

  int NB = (N + 255) >> 8;
  k_hist<<<256, 256, 0, stream>>>(dstp, bhist, E);
  k_bscan<<<1, 256, 0, stream>>>(bhist, bbase, gcur, rowptr, N, E);
  k_part<<<(E + PCHUNK - 1) / PCHUNK, 256, 0, stream>>>(src, dstp, ew, gcur, tmp, E);
  k_bsort<<<NB, 256, 0, stream>>>(tmp, bbase, epair, rowptr, N);

  int bnb = ((size_t)N * (SP/2) + 255) / 256;
  k_bn_apply<<<bnb, 256, 0, stream>>>(h, misc, bufA, N);

  int gb = (N + 63) / 64;
  int ab = (N + 3) / 4;

  for (int l = 0; l < 3; l++){
    k_mm<<<gb, 256, 0, stream>>>(bufA, W0p + l * 7680, W1p + l * 7680, W2p + l * 7680,
                                 asl[l], adl[l], bufB, a_src, a_dst, N);
    k_agg<<<ab, 256, 0, stream>>>(bufB, a_src, a_dst, rowptr, epair, misc, l, bl[l], bufA, N);
  }

  k_fcl<false><<<gb, 256, 0, stream>>>(bufA, FW0p + 0 * 7680, FW1p + 0 * 7680, FW2p + 0 * 7680, fb[0], bufB, N);
  k_fcl<false><<<gb, 256, 0, stream>>>(bufB, FW0p + 1 * 7680, FW1p + 1 * 7680, FW2p + 1 * 7680, fb[1], bufA, N);
  k_fcl<false><<<gb, 256, 0, stream>>>(bufA, FW0p + 2 * 7680, FW1p + 2 * 7680, FW2p + 2 * 7680, fb[2], bufB, N);
  k_fcl<false><<<gb, 256, 0, stream>>>(bufB, FW0p + 3 * 7680, FW1p + 3 * 7680, FW2p + 3 * 7680, fb[3], bufA, N);
  k_fcl<true ><<<gb, 256, 0, stream>>>(bufA, FW0p + 4 * 7680, FW1p + 4 * 7680, FW2p + 4 * 7680, fb[4], (float*)d_out, N);
}

// Round 9
// 475.437 us; speedup vs baseline: 1.6214x; 1.0314x over previous
//
#include <hip/hip_runtime.h>
#include <math.h>

#define D 66
#define SP 68                 // padded fp32 row stride, 16B-aligned rows, cols 66,67 always 0
#define NEG_SLOPE 0.2f
#define CAP 6144

typedef short s8v __attribute__((ext_vector_type(8)));   // 8 bf16 bit-patterns = 4 VGPRs
typedef float f4v __attribute__((ext_vector_type(4)));

__device__ __forceinline__ float lrelu(float a){ return a > 0.f ? a : NEG_SLOPE * a; }
__device__ __forceinline__ void fma4(float4& a, float s, const float4& w){
  a.x = fmaf(s, w.x, a.x); a.y = fmaf(s, w.y, a.y);
  a.z = fmaf(s, w.z, a.z); a.w = fmaf(s, w.w, a.w);
}
__device__ __forceinline__ unsigned short bf16r(float f){   // RNE f32->bf16
  unsigned u = __float_as_uint(f);
  u += 0x7FFFu + ((u >> 16) & 1u);
  return (unsigned short)(u >> 16);
}
__device__ __forceinline__ float bf16f(unsigned short b){
  return __uint_as_float(((unsigned)b) << 16);
}
// 3-term bf16 split: v = a0 + a1 + a2 (+ O(2^-27 |v|))
__device__ __forceinline__ void split8(const float* p, s8v& a0, s8v& a1, s8v& a2){
  #pragma unroll
  for (int j = 0; j < 8; j++){
    float v = p[j];
    unsigned short b0 = bf16r(v);  float f0 = bf16f(b0);
    float r1 = v - f0;
    unsigned short b1 = bf16r(r1); float f1 = bf16f(b1);
    unsigned short b2 = bf16r(r1 - f1);
    a0[j] = (short)b0; a1[j] = (short)b1; a2[j] = (short)b2;
  }
}
#define MM6(acc, a0, a1, a2, b0v, b1v, b2v)                                \
  acc = __builtin_amdgcn_mfma_f32_16x16x32_bf16(a0, b0v, acc, 0, 0, 0);    \
  acc = __builtin_amdgcn_mfma_f32_16x16x32_bf16(a1, b0v, acc, 0, 0, 0);    \
  acc = __builtin_amdgcn_mfma_f32_16x16x32_bf16(a0, b1v, acc, 0, 0, 0);    \
  acc = __builtin_amdgcn_mfma_f32_16x16x32_bf16(a2, b0v, acc, 0, 0, 0);    \
  acc = __builtin_amdgcn_mfma_f32_16x16x32_bf16(a1, b1v, acc, 0, 0, 0);    \
  acc = __builtin_amdgcn_mfma_f32_16x16x32_bf16(a0, b2v, acc, 0, 0, 0);

// ---------------- BatchNorm ----------------
__global__ __launch_bounds__(256) void k_bn_stats(const float* __restrict__ h,
                                                  float* __restrict__ sums, int n){
  __shared__ float ls[2 * D];
  int t = threadIdx.x;
  if (t < 2 * D) ls[t] = 0.f;
  __syncthreads();
  int rpb = (n + gridDim.x - 1) / gridDim.x;
  int r0 = blockIdx.x * rpb;
  int r1 = min(n, r0 + rpb);
  if (t < 3 * D){
    int c = t % D, seg = t / D;
    float s1 = 0.f, s2 = 0.f;
    for (int r = r0 + seg; r < r1; r += 3){
      float v = h[(size_t)r * D + c];
      s1 += v; s2 += v * v;
    }
    atomicAdd(&ls[c], s1);
    atomicAdd(&ls[D + c], s2);
  }
  __syncthreads();
  if (t < 2 * D) atomicAdd(&sums[t], ls[t]);
}

__global__ void k_bn_finalize(const float* __restrict__ sums,
                              const float* __restrict__ gamma, const float* __restrict__ beta,
                              const float* __restrict__ We1, const float* __restrict__ ae1,
                              const float* __restrict__ We2, const float* __restrict__ ae2,
                              const float* __restrict__ We3, const float* __restrict__ ae3,
                              float* __restrict__ misc, int n){
  int t = threadIdx.x;
  if (t < D){
    float mean = sums[t] / (float)n;
    float var  = sums[D + t] / (float)n - mean * mean;
    float inv  = rsqrtf(var + 1e-5f);
    float sc = gamma[t] * inv;
    misc[t] = sc;
    misc[D + t] = beta[t] - mean * sc;
  } else if (t == D){
    float c = 0.f; for (int d = 0; d < D; d++) c += We1[d] * ae1[d]; misc[2*D + 0] = c;
  } else if (t == D + 1){
    float c = 0.f; for (int d = 0; d < D; d++) c += We2[d] * ae2[d]; misc[2*D + 1] = c;
  } else if (t == D + 2){
    float c = 0.f; for (int d = 0; d < D; d++) c += We3[d] * ae3[d]; misc[2*D + 2] = c;
  }
}

// BN apply -> SP-padded fp32 (cols 66,67 = 0)
__global__ __launch_bounds__(256) void k_bn_apply(const float* __restrict__ h, const float* __restrict__ misc,
                                                  float* __restrict__ x, int n){
  int i = blockIdx.x * 256 + threadIdx.x;
  int r = i / (SP/2), c2 = i - r * (SP/2);
  if (r >= n) return;
  int c = 2 * c2;
  float2 v = make_float2(0.f, 0.f);
  if (c < D){
    float2 hv = *(const float2*)&h[(size_t)r * D + c];
    v.x = hv.x * misc[c]     + misc[D + c];
    v.y = hv.y * misc[c + 1] + misc[D + c + 1];
  }
  *(float2*)&x[(size_t)r * SP + c] = v;
}

// ---------------- GAT weight pre-pack into MFMA B-fragment layout (bf16 3-term) ----------------
__global__ __launch_bounds__(256) void k_pack(const float* __restrict__ w0, const float* __restrict__ w1,
                                              const float* __restrict__ w2,
                                              short* __restrict__ W0, short* __restrict__ W1,
                                              short* __restrict__ W2){
  int tid = blockIdx.x * 256 + threadIdx.x;
  if (tid >= 3 * 15 * 64) return;
  int L = tid & 63;
  int ct = (tid >> 6) % 15;
  int lay = tid / 960;
  const float* w = (lay == 0) ? w0 : ((lay == 1) ? w1 : w2);
  int c = ct / 5, t = ct % 5;
  int nn = t * 16 + (L & 15);
  int kb = c * 32 + (L >> 4) * 8;
  #pragma unroll
  for (int j = 0; j < 8; j++){
    int k = kb + j;
    float v = (k < D && nn < D) ? w[k * D + nn] : 0.f;
    unsigned short b0 = bf16r(v);  float f0 = bf16f(b0);
    float r1 = v - f0;
    unsigned short b1 = bf16r(r1); float f1 = bf16f(b1);
    unsigned short b2 = bf16r(r1 - f1);
    W0[tid * 8 + j] = (short)b0;
    W1[tid * 8 + j] = (short)b1;
    W2[tid * 8 + j] = (short)b2;
  }
}

// FC weight + bias pre-pack (5 layers, last has ncol=22; bpack zero-padded to 80 cols)
__global__ __launch_bounds__(256) void k_packfc(const float* __restrict__ w0, const float* __restrict__ w1,
                                                const float* __restrict__ w2, const float* __restrict__ w3,
                                                const float* __restrict__ w4,
                                                const float* __restrict__ b0, const float* __restrict__ b1,
                                                const float* __restrict__ b2, const float* __restrict__ b3,
                                                const float* __restrict__ b4,
                                                short* __restrict__ W0, short* __restrict__ W1,
                                                short* __restrict__ W2, float* __restrict__ bpack){
  int tid = blockIdx.x * 256 + threadIdx.x;
  if (tid < 5 * 15 * 64){
    int L = tid & 63;
    int ct = (tid >> 6) % 15;
    int lay = tid / 960;
    const float* w = (lay == 0) ? w0 : (lay == 1) ? w1 : (lay == 2) ? w2 : (lay == 3) ? w3 : w4;
    int ncol = (lay == 4) ? 22 : D;
    int c = ct / 5, t = ct % 5;
    int nn = t * 16 + (L & 15);
    int kb = c * 32 + (L >> 4) * 8;
    #pragma unroll
    for (int j = 0; j < 8; j++){
      int k = kb + j;
      float v = (k < D && nn < ncol) ? w[k * ncol + nn] : 0.f;
      unsigned short bb0 = bf16r(v);  float f0 = bf16f(bb0);
      float r1 = v - f0;
      unsigned short bb1 = bf16r(r1); float f1 = bf16f(bb1);
      unsigned short bb2 = bf16r(r1 - f1);
      W0[tid * 8 + j] = (short)bb0;
      W1[tid * 8 + j] = (short)bb1;
      W2[tid * 8 + j] = (short)bb2;
    }
  } else if (tid < 5 * 15 * 64 + 400){
    int i = tid - 5 * 15 * 64;
    int lay = i / 80, col = i % 80;
    const float* b = (lay == 0) ? b0 : (lay == 1) ? b1 : (lay == 2) ? b2 : (lay == 3) ? b3 : b4;
    int ncol = (lay == 4) ? 22 : D;
    bpack[i] = (col < ncol) ? b[col] : 0.f;
  }
}

// ---------------- CSR build: binned counting sort ----------------
__global__ __launch_bounds__(256) void k_hist(const int* __restrict__ dst,
                                              int* __restrict__ bhist, int E){
  __shared__ int h[256];
  int t = threadIdx.x;
  h[t] = 0;
  __syncthreads();
  int stride = gridDim.x * blockDim.x;
  for (int e = blockIdx.x * blockDim.x + t; e < E; e += stride)
    atomicAdd(&h[dst[e] >> 8], 1);
  __syncthreads();
  if (h[t]) atomicAdd(&bhist[t], h[t]);
}

__global__ void k_bscan(const int* __restrict__ bhist, int* __restrict__ bbase,
                        int* __restrict__ gcur, int* __restrict__ rowptr, int N, int E){
  __shared__ int sh[256];
  int t = threadIdx.x;
  int v = bhist[t];
  sh[t] = v; __syncthreads();
  for (int o = 1; o < 256; o <<= 1){
    int u = (t >= o) ? sh[t - o] : 0;
    __syncthreads();
    sh[t] += u;
    __syncthreads();
  }
  int ex = sh[t] - v;
  bbase[t] = ex;
  gcur[t] = ex;
  if (t == 255){ bbase[256] = sh[255]; rowptr[N] = E; }
}

#define PCHUNK 4096
__global__ __launch_bounds__(256) void k_part(const int* __restrict__ src, const int* __restrict__ dst,
                                              const float* __restrict__ ew,
                                              int* __restrict__ gcur, int2* __restrict__ tmp, int E){
  __shared__ int hist[256];
  __shared__ int base[256];
  int t = threadIdx.x;
  int e0 = blockIdx.x * PCHUNK;
  int eend = min(E, e0 + PCHUNK);
  hist[t] = 0;
  __syncthreads();
  for (int e = e0 + t; e < eend; e += 256)
    atomicAdd(&hist[dst[e] >> 8], 1);
  __syncthreads();
  if (hist[t] > 0) base[t] = atomicAdd(&gcur[t], hist[t]);
  hist[t] = 0;
  __syncthreads();
  for (int e = e0 + t; e < eend; e += 256){
    int d = dst[e];
    int b = d >> 8;
    int off = atomicAdd(&hist[b], 1);
    tmp[base[b] + off] = make_int2((src[e] & 0xffff) | ((d & 255) << 16), __float_as_int(ew[e]));
  }
}

__global__ __launch_bounds__(256) void k_bsort(const int2* __restrict__ tmp, const int* __restrict__ bbase,
                                               int2* __restrict__ epair, int* __restrict__ rowptr, int N){
  __shared__ int2 ebuf[CAP];
  __shared__ int lcnt[256];
  __shared__ int sc[256];
  __shared__ int lcur[256];
  int b = blockIdx.x, t = threadIdx.x;
  int s0 = bbase[b], s1 = bbase[b + 1];
  int cnt = s1 - s0;
  lcnt[t] = 0;
  __syncthreads();
  for (int j = t; j < cnt; j += 256){
    int2 e = tmp[s0 + j];
    if (j < CAP) ebuf[j] = e;
    atomicAdd(&lcnt[(e.x >> 16) & 255], 1);
  }
  __syncthreads();
  int v = lcnt[t];
  sc[t] = v; __syncthreads();
  for (int o = 1; o < 256; o <<= 1){
    int u = (t >= o) ? sc[t - o] : 0;
    __syncthreads();
    sc[t] += u;
    __syncthreads();
  }
  int ex = sc[t] - v;
  int node = (b << 8) + t;
  if (node < N) rowptr[node] = s0 + ex;
  lcur[t] = ex;
  __syncthreads();
  for (int j = t; j < cnt; j += 256){
    int2 e = (j < CAP) ? ebuf[j] : tmp[s0 + j];
    int i = (e.x >> 16) & 255;
    int p = atomicAdd(&lcur[i], 1);
    epair[s0 + p] = make_int2(e.x & 0xffff, e.y);
  }
}

// ---------------- GAT GEMM via 3-term bf16 MFMA: Y = X@W (+att dots), no LDS ----------------
__global__ __launch_bounds__(256) void k_mm(const float* __restrict__ X,
    const short* __restrict__ W0, const short* __restrict__ W1, const short* __restrict__ W2,
    const float* __restrict__ att_s, const float* __restrict__ att_d,
    float* __restrict__ Y, float* __restrict__ a_src, float* __restrict__ a_dst, int n){
  const int wv = threadIdx.x >> 6, L = threadIdx.x & 63;
  const int quad = L >> 4, m = L & 15;
  const int row0 = blockIdx.x * 64 + wv * 16;
  const int lrow = min(row0 + m, n - 1);
  const float* xr = X + (size_t)lrow * SP;
  f4v acc[5];
  #pragma unroll
  for (int t = 0; t < 5; t++) acc[t] = (f4v){0.f,0.f,0.f,0.f};

  #pragma unroll
  for (int c = 0; c < 3; c++){
    float xv[8];
    if (c < 2){
      float4 p0 = *(const float4*)&xr[c * 32 + quad * 8];
      float4 p1 = *(const float4*)&xr[c * 32 + quad * 8 + 4];
      xv[0] = p0.x; xv[1] = p0.y; xv[2] = p0.z; xv[3] = p0.w;
      xv[4] = p1.x; xv[5] = p1.y; xv[6] = p1.z; xv[7] = p1.w;
    } else {
      float4 p0 = make_float4(0.f, 0.f, 0.f, 0.f);
      if (quad == 0) p0 = *(const float4*)&xr[64];   // cols 64,65 real; 66,67 stored zeros
      xv[0] = p0.x; xv[1] = p0.y; xv[2] = p0.z; xv[3] = p0.w;
      xv[4] = 0.f; xv[5] = 0.f; xv[6] = 0.f; xv[7] = 0.f;
    }
    s8v a0, a1, a2;
    split8(xv, a0, a1, a2);
    const short* b0p = W0 + (c * 5) * 512 + L * 8;
    const short* b1p = W1 + (c * 5) * 512 + L * 8;
    const short* b2p = W2 + (c * 5) * 512 + L * 8;
    #pragma unroll
    for (int t = 0; t < 5; t++){
      s8v b0v = *(const s8v*)(b0p + t * 512);
      s8v b1v = *(const s8v*)(b1p + t * 512);
      s8v b2v = *(const s8v*)(b2p + t * 512);
      MM6(acc[t], a0, a1, a2, b0v, b1v, b2v)
    }
  }

  float ps[4] = {0.f,0.f,0.f,0.f}, pd[4] = {0.f,0.f,0.f,0.f};
  #pragma unroll
  for (int t = 0; t < 5; t++){
    int col = t * 16 + m;
    float as_v = 0.f, ad_v = 0.f;
    if (col < D){ as_v = att_s[col]; ad_v = att_d[col]; }
    #pragma unroll
    for (int r = 0; r < 4; r++){
      ps[r] += acc[t][r] * as_v;
      pd[r] += acc[t][r] * ad_v;
    }
  }
  #pragma unroll
  for (int r = 0; r < 4; r++){
    int rw = row0 + quad * 4 + r;
    if (rw < n){
      float* yr = Y + (size_t)rw * SP;
      #pragma unroll
      for (int t = 0; t < 4; t++) yr[t * 16 + m] = acc[t][r];
      if (m < 4) yr[64 + m] = (m < 2) ? acc[4][r] : 0.f;
    }
  }
  #pragma unroll
  for (int o = 1; o <= 8; o <<= 1){
    #pragma unroll
    for (int r = 0; r < 4; r++){
      ps[r] += __shfl_xor(ps[r], o);
      pd[r] += __shfl_xor(pd[r], o);
    }
  }
  if (m == 0){
    #pragma unroll
    for (int r = 0; r < 4; r++){
      int rw = row0 + quad * 4 + r;
      if (rw < n){ a_src[rw] = ps[r]; a_dst[rw] = pd[r]; }
    }
  }
}

// ---------------- Fused 5-layer FC head via 3-term bf16 MFMA; fp32 LDS bounce ----------------
// Each wave owns its 16 rows end-to-end; LDS is per-wave private (no cross-wave sharing).
#define FST 84
__global__ __launch_bounds__(256) void k_fcmm(const float* __restrict__ X,
    const short* __restrict__ W0, const short* __restrict__ W1, const short* __restrict__ W2,
    const float* __restrict__ bpack, float* __restrict__ out, int n){
  __shared__ __align__(16) float xs[4][16][FST];
  const int wv = threadIdx.x >> 6, L = threadIdx.x & 63;
  const int quad = L >> 4, m = L & 15;
  const int row0 = blockIdx.x * 64 + wv * 16;
  const int lrow = min(row0 + m, n - 1);
  const float* xr = X + (size_t)lrow * SP;

  for (int l = 0; l < 5; l++){
    const int NTl = (l == 4) ? 2 : 5;
    f4v acc[5];
    #pragma unroll
    for (int t = 0; t < 5; t++) acc[t] = (f4v){0.f,0.f,0.f,0.f};
    #pragma unroll
    for (int c = 0; c < 3; c++){
      float xv[8];
      if (l == 0){
        if (c < 2){
          float4 p0 = *(const float4*)&xr[c * 32 + quad * 8];
          float4 p1 = *(const float4*)&xr[c * 32 + quad * 8 + 4];
          xv[0] = p0.x; xv[1] = p0.y; xv[2] = p0.z; xv[3] = p0.w;
          xv[4] = p1.x; xv[5] = p1.y; xv[6] = p1.z; xv[7] = p1.w;
        } else {
          float4 p0 = make_float4(0.f, 0.f, 0.f, 0.f);
          if (quad == 0) p0 = *(const float4*)&xr[64];
          xv[0] = p0.x; xv[1] = p0.y; xv[2] = p0.z; xv[3] = p0.w;
          xv[4] = 0.f; xv[5] = 0.f; xv[6] = 0.f; xv[7] = 0.f;
        }
      } else {
        if (c == 2 && quad >= 2){
          #pragma unroll
          for (int j = 0; j < 8; j++) xv[j] = 0.f;   // k=80..95: stay in-bounds; B is 0 there anyway
        } else {
          float4 p0 = *(const float4*)&xs[wv][m][c * 32 + quad * 8];
          float4 p1 = *(const float4*)&xs[wv][m][c * 32 + quad * 8 + 4];
          xv[0] = p0.x; xv[1] = p0.y; xv[2] = p0.z; xv[3] = p0.w;
          xv[4] = p1.x; xv[5] = p1.y; xv[6] = p1.z; xv[7] = p1.w;
        }
      }
      s8v a0, a1, a2;
      split8(xv, a0, a1, a2);
      const short* b0p = W0 + ((l * 3 + c) * 5) * 512 + L * 8;
      const short* b1p = W1 + ((l * 3 + c) * 5) * 512 + L * 8;
      const short* b2p = W2 + ((l * 3 + c) * 5) * 512 + L * 8;
      for (int t = 0; t < NTl; t++){
        s8v b0v = *(const s8v*)(b0p + t * 512);
        s8v b1v = *(const s8v*)(b1p + t * 512);
        s8v b2v = *(const s8v*)(b2p + t * 512);
        MM6(acc[t], a0, a1, a2, b0v, b1v, b2v)
      }
    }
    if (l < 4){
      __syncthreads();
      #pragma unroll
      for (int t = 0; t < 5; t++){
        int col = t * 16 + m;
        float bv = bpack[l * 80 + col];   // padded cols: acc=0, bv=0 -> relu(0)=0
        #pragma unroll
        for (int r = 0; r < 4; r++){
          float v = acc[t][r] + bv;
          xs[wv][quad * 4 + r][col] = v > 0.f ? v : 0.f;
        }
      }
      __syncthreads();
    } else {
      #pragma unroll
      for (int t = 0; t < 2; t++){
        int col = t * 16 + m;
        #pragma unroll
        for (int r = 0; r < 4; r++){
          int rw = row0 + quad * 4 + r;
          if (col < 22 && rw < n) out[(size_t)rw * 22 + col] = acc[t][r] + bpack[4 * 80 + col];
        }
      }
    }
  }
}

// ---------------- GAT softmax + aggregate: one wave per dst node, 8 edges/iter ----------------
// NOTE: all __shfl calls are OUTSIDE divergent guards (ds_bpermute from an inactive
// source lane is undefined — this was the rounds-4..6 bug).
__global__ __launch_bounds__(256) void k_agg(const float* __restrict__ y,
                                             const float* __restrict__ a_src, const float* __restrict__ a_dst,
                                             const int* __restrict__ rowptr, const int2* __restrict__ epair,
                                             const float* __restrict__ misc, int cidx,
                                             const float* __restrict__ bias,
                                             float* __restrict__ xout, int n){
  const int wid  = (int)((blockIdx.x * (size_t)blockDim.x + threadIdx.x) >> 6);
  const int lane = threadIdx.x & 63;
  if (wid >= n) return;
  const int beg = rowptr[wid];
  const int deg = rowptr[wid + 1] - beg;
  const float ce  = misc[2 * D + cidx];
  const float adn = a_dst[wid];
  const int g = lane >> 3, q = lane & 7;   // g: edge sub-index, q: col group

  float4 accA = make_float4(0.f,0.f,0.f,0.f);   // cols 4q   .. 4q+3   (0..31)
  float4 accB = make_float4(0.f,0.f,0.f,0.f);   // cols 32+4q.. 35+4q  (32..63)
  float2 tacc = make_float2(0.f,0.f);           // cols 64,65 (q==0 lanes)

  if (deg <= 64){
    int s = 0; float al = -INFINITY;
    bool act = lane < deg;
    if (act){
      int2 ep = epair[beg + lane];
      s = ep.x;
      al = lrelu(a_src[s] + adn + ce * __int_as_float(ep.y));
    }
    float mx = al;
    #pragma unroll
    for (int o = 32; o; o >>= 1) mx = fmaxf(mx, __shfl_xor(mx, o));
    float ex = act ? __expf(al - mx) : 0.f;
    float sum = ex;
    #pragma unroll
    for (int o = 32; o; o >>= 1) sum += __shfl_xor(sum, o);
    float coef = ex * (1.f / (sum + 1e-16f));   // 0 for inactive lanes
    for (int e0 = 0; e0 < deg; e0 += 8){
      int e = e0 + g;                 // valid lane index 0..63 always
      int   st = __shfl(s, e);        // unguarded: every source lane active
      float ct = __shfl(coef, e);
      if (e < deg){                   // uniform per 8-lane cluster
        const float* row = y + (size_t)st * SP;
        float4 y0 = *(const float4*)&row[4 * q];
        float4 y1 = *(const float4*)&row[32 + 4 * q];
        fma4(accA, ct, y0);
        fma4(accB, ct, y1);
        if (q == 0){
          float2 tv = *(const float2*)&row[64];
          tacc.x += ct * tv.x; tacc.y += ct * tv.y;
        }
      }
    }
  } else {
    float mx = -INFINITY;
    for (int j0 = 0; j0 < deg; j0 += 64){
      int j = j0 + lane;
      if (j < deg){
        int2 ep = epair[beg + j];
        mx = fmaxf(mx, lrelu(a_src[ep.x] + adn + ce * __int_as_float(ep.y)));
      }
    }
    #pragma unroll
    for (int o = 32; o; o >>= 1) mx = fmaxf(mx, __shfl_xor(mx, o));
    float sum = 0.f;
    for (int j0 = 0; j0 < deg; j0 += 64){
      int j = j0 + lane;
      if (j < deg){
        int2 ep = epair[beg + j];
        sum += __expf(lrelu(a_src[ep.x] + adn + ce * __int_as_float(ep.y)) - mx);
      }
    }
    #pragma unroll
    for (int o = 32; o; o >>= 1) sum += __shfl_xor(sum, o);
    float inv = 1.f / (sum + 1e-16f);
    for (int j0 = 0; j0 < deg; j0 += 64){
      int cnt = min(64, deg - j0);
      int s = 0; float ex = 0.f;
      if (lane < cnt){
        int2 ep = epair[beg + j0 + lane];
        s = ep.x;
        ex = __expf(lrelu(a_src[s] + adn + ce * __int_as_float(ep.y)) - mx);
      }
      float coef = ex * inv;          // 0 for lanes >= cnt
      for (int e0 = 0; e0 < cnt; e0 += 8){
        int e = e0 + g;
        int   st = __shfl(s, e);      // unguarded
        float ct = __shfl(coef, e);
        if (e < cnt){
          const float* row = y + (size_t)st * SP;
          float4 y0 = *(const float4*)&row[4 * q];
          float4 y1 = *(const float4*)&row[32 + 4 * q];
          fma4(accA, ct, y0);
          fma4(accB, ct, y1);
          if (q == 0){
            float2 tv = *(const float2*)&row[64];
            tacc.x += ct * tv.x; tacc.y += ct * tv.y;
          }
        }
      }
    }
  }

  // reduce across the 8 edge-groups (lane bits 3..5)
  #pragma unroll
  for (int o = 8; o <= 32; o <<= 1){
    accA.x += __shfl_xor(accA.x, o); accA.y += __shfl_xor(accA.y, o);
    accA.z += __shfl_xor(accA.z, o); accA.w += __shfl_xor(accA.w, o);
    accB.x += __shfl_xor(accB.x, o); accB.y += __shfl_xor(accB.y, o);
    accB.z += __shfl_xor(accB.z, o); accB.w += __shfl_xor(accB.w, o);
    tacc.x += __shfl_xor(tacc.x, o); tacc.y += __shfl_xor(tacc.y, o);
  }
  float* orow = xout + (size_t)wid * SP;
  if (lane < 8){
    float4 v;
    v.x = accA.x + bias[4*lane+0]; v.x = v.x > 0.f ? v.x : 0.f;
    v.y = accA.y + bias[4*lane+1]; v.y = v.y > 0.f ? v.y : 0.f;
    v.z = accA.z + bias[4*lane+2]; v.z = v.z > 0.f ? v.z : 0.f;
    v.w = accA.w + bias[4*lane+3]; v.w = v.w > 0.f ? v.w : 0.f;
    *(float4*)&orow[4 * lane] = v;
  } else if (lane < 16){
    int qq = lane - 8;
    float4 v;
    v.x = accB.x + bias[32+4*qq+0]; v.x = v.x > 0.f ? v.x : 0.f;
    v.y = accB.y + bias[32+4*qq+1]; v.y = v.y > 0.f ? v.y : 0.f;
    v.z = accB.z + bias[32+4*qq+2]; v.z = v.z > 0.f ? v.z : 0.f;
    v.w = accB.w + bias[32+4*qq+3]; v.w = v.w > 0.f ? v.w : 0.f;
    *(float4*)&orow[32 + 4 * qq] = v;
  }
  if (lane == 0){
    float4 tv;
    tv.x = tacc.x + bias[64]; tv.x = tv.x > 0.f ? tv.x : 0.f;
    tv.y = tacc.y + bias[65]; tv.y = tv.y > 0.f ? tv.y : 0.f;
    tv.z = 0.f; tv.w = 0.f;
    *(float4*)&orow[64] = tv;
  }
}

// ---------------- launch ----------------
extern "C" void kernel_launch(void* const* d_in, const int* in_sizes, int n_in,
                              void* d_out, int out_size, void* d_ws, size_t ws_size,
                              hipStream_t stream){
  const float* h     = (const float*)d_in[0];
  const int*   ei    = (const int*)  d_in[1];
  const float* ew    = (const float*)d_in[2];
  const float* gamma = (const float*)d_in[3];
  const float* beta  = (const float*)d_in[4];
  const float *Wl[3], *bl[3], *asl[3], *adl[3], *Wel[3], *ael[3];
  int idx = 5;
  for (int l = 0; l < 3; l++){
    Wl[l]  = (const float*)d_in[idx++];
    bl[l]  = (const float*)d_in[idx++];
    asl[l] = (const float*)d_in[idx++];
    adl[l] = (const float*)d_in[idx++];
    Wel[l] = (const float*)d_in[idx++];
    ael[l] = (const float*)d_in[idx++];
  }
  const float *fw[5], *fb[5];
  for (int l = 0; l < 5; l++){ fw[l] = (const float*)d_in[idx++]; fb[l] = (const float*)d_in[idx++]; }

  int N = in_sizes[0] / D;
  int E = in_sizes[1] / 2;
  const int* src  = ei;
  const int* dstp = ei + E;

  char* base = (char*)d_ws;
  size_t o = 0;
  auto alloc = [&](size_t b){ size_t r = o; o += (b + 255) & ~(size_t)255; return r; };
  float*  bufA   = (float*)(base + alloc((size_t)N * SP * 4));
  float*  bufB   = (float*)(base + alloc((size_t)N * SP * 4));
  float*  a_src  = (float*)(base + alloc((size_t)N * 4));
  float*  a_dst  = (float*)(base + alloc((size_t)N * 4));
  float*  misc   = (float*)(base + alloc(512 * 4));
  float*  sums   = (float*)(base + alloc(2 * D * 4));
  int*    rowptr = (int*)  (base + alloc((size_t)(N + 1) * 4));
  int*    bhist  = (int*)  (base + alloc(256 * 4));
  int*    bbase  = (int*)  (base + alloc(257 * 4));
  int*    gcur   = (int*)  (base + alloc(256 * 4));
  int2*   epair  = (int2*) (base + alloc((size_t)E * 8));
  short*  W0p    = (short*)(base + alloc(3 * 7680 * 2));
  short*  W1p    = (short*)(base + alloc(3 * 7680 * 2));
  short*  W2p    = (short*)(base + alloc(3 * 7680 * 2));
  short*  FW0p   = (short*)(base + alloc(5 * 7680 * 2));
  short*  FW1p   = (short*)(base + alloc(5 * 7680 * 2));
  short*  FW2p   = (short*)(base + alloc(5 * 7680 * 2));
  float*  bpack  = (float*)(base + alloc(400 * 4));
  int2*   tmp    = (int2*)bufB;   // alias: bufB unused until first k_mm

  hipMemsetAsync(sums, 0, 2 * D * 4, stream);
  hipMemsetAsync(bhist, 0, 256 * 4, stream);

  k_bn_stats<<<256, 256, 0, stream>>>(h, sums, N);
  k_bn_finalize<<<1, 128, 0, stream>>>(sums, gamma, beta, Wel[0], ael[0], Wel[1], ael[1], Wel[2], ael[2], misc, N);
  k_pack<<<12, 256, 0, stream>>>(Wl[0], Wl[1], Wl[2], W0p, W1p, W2p);
  k_packfc<<<21, 256, 0, stream>>>(fw[0], fw[1], fw[2], fw[3], fw[4],
                                   fb[0], fb[1], fb[2], fb[3], fb[4],
                                   FW0p, FW1p, FW2p, bpack);

  int NB = (N + 255) >> 8;
  k_hist<<<256, 256, 0, stream>>>(dstp, bhist, E);
  k_bscan<<<1, 256, 0, stream>>>(bhist, bbase, gcur, rowptr, N, E);
  k_part<<<(E + PCHUNK - 1) / PCHUNK, 256, 0, stream>>>(src, dstp, ew, gcur, tmp, E);
  k_bsort<<<NB, 256, 0, stream>>>(tmp, bbase, epair, rowptr, N);

  int bnb = ((size_t)N * (SP/2) + 255) / 256;
  k_bn_apply<<<bnb, 256, 0, stream>>>(h, misc, bufA, N);

  int gb = (N + 63) / 64;
  int ab = (N + 3) / 4;

  for (int l = 0; l < 3; l++){
    k_mm<<<gb, 256, 0, stream>>>(bufA, W0p + l * 7680, W1p + l * 7680, W2p + l * 7680,
                                 asl[l], adl[l], bufB, a_src, a_dst, N);
    k_agg<<<ab, 256, 0, stream>>>(bufB, a_src, a_dst, rowptr, epair, misc, l, bl[l], bufA, N);
  }

  k_fcmm<<<gb, 256, 0, stream>>>(bufA, FW0p, FW1p, FW2p, bpack, (float*)d_out, N);
}

// Round 10
// 445.539 us; speedup vs baseline: 1.7302x; 1.0671x over previous
//
#include <hip/hip_runtime.h>
#include <math.h>

#define D 66
#define SP 68                 // padded fp32 row stride, 16B-aligned rows, cols 66,67 always 0
#define NEG_SLOPE 0.2f
#define CAP 6144

typedef short s8v __attribute__((ext_vector_type(8)));   // 8 bf16 bit-patterns = 4 VGPRs
typedef float f4v __attribute__((ext_vector_type(4)));

__device__ __forceinline__ float lrelu(float a){ return a > 0.f ? a : NEG_SLOPE * a; }
__device__ __forceinline__ void fma4(float4& a, float s, const float4& w){
  a.x = fmaf(s, w.x, a.x); a.y = fmaf(s, w.y, a.y);
  a.z = fmaf(s, w.z, a.z); a.w = fmaf(s, w.w, a.w);
}
__device__ __forceinline__ unsigned short bf16r(float f){   // RNE f32->bf16 (pack-time only)
  unsigned u = __float_as_uint(f);
  u += 0x7FFFu + ((u >> 16) & 1u);
  return (unsigned short)(u >> 16);
}
__device__ __forceinline__ float bf16f(unsigned short b){
  return __uint_as_float(((unsigned)b) << 16);
}
// truncation 3-term split: v = a0 + a1 + a2 + r, |r| <= 2^-24 |v|; each step is EXACT
// (f0 = v with low mantissa bits zeroed -> r1 = v - f0 exact). ~7 VALU ops/element.
__device__ __forceinline__ void split8t(const float* p, s8v& a0, s8v& a1, s8v& a2){
  #pragma unroll
  for (int j = 0; j < 8; j++){
    float v = p[j];
    unsigned u0 = __float_as_uint(v) & 0xFFFF0000u;
    float r1 = v - __uint_as_float(u0);
    unsigned u1 = __float_as_uint(r1) & 0xFFFF0000u;
    float r2 = r1 - __uint_as_float(u1);
    unsigned u2 = __float_as_uint(r2);
    a0[j] = (short)(u0 >> 16);
    a1[j] = (short)(u1 >> 16);
    a2[j] = (short)(u2 >> 16);
  }
}
#define MM6(acc, a0, a1, a2, b0v, b1v, b2v)                                \
  acc = __builtin_amdgcn_mfma_f32_16x16x32_bf16(a0, b0v, acc, 0, 0, 0);    \
  acc = __builtin_amdgcn_mfma_f32_16x16x32_bf16(a1, b0v, acc, 0, 0, 0);    \
  acc = __builtin_amdgcn_mfma_f32_16x16x32_bf16(a0, b1v, acc, 0, 0, 0);    \
  acc = __builtin_amdgcn_mfma_f32_16x16x32_bf16(a2, b0v, acc, 0, 0, 0);    \
  acc = __builtin_amdgcn_mfma_f32_16x16x32_bf16(a1, b1v, acc, 0, 0, 0);    \
  acc = __builtin_amdgcn_mfma_f32_16x16x32_bf16(a0, b2v, acc, 0, 0, 0);

// ---------------- BN stats + bucket hist (merged; blocks 0..255 = BN, 256..511 = hist) ----------------
__global__ __launch_bounds__(256) void k_stats_hist(const float* __restrict__ h, const int* __restrict__ dst,
                                                    float* __restrict__ sums, int* __restrict__ bhist,
                                                    int n, int E){
  int t = threadIdx.x;
  if (blockIdx.x < 256){
    __shared__ float ls[2 * D];
    if (t < 2 * D) ls[t] = 0.f;
    __syncthreads();
    int rpb = (n + 255) / 256;
    int r0 = blockIdx.x * rpb;
    int r1 = min(n, r0 + rpb);
    if (t < 3 * D){
      int c = t % D, seg = t / D;
      float s1 = 0.f, s2 = 0.f;
      for (int r = r0 + seg; r < r1; r += 3){
        float v = h[(size_t)r * D + c];
        s1 += v; s2 += v * v;
      }
      atomicAdd(&ls[c], s1);
      atomicAdd(&ls[D + c], s2);
    }
    __syncthreads();
    if (t < 2 * D) atomicAdd(&sums[t], ls[t]);
  } else {
    __shared__ int hh[256];
    hh[t] = 0;
    __syncthreads();
    int stride = 256 * 256;
    for (int e = (blockIdx.x - 256) * 256 + t; e < E; e += stride)
      atomicAdd(&hh[dst[e] >> 8], 1);
    __syncthreads();
    if (hh[t]) atomicAdd(&bhist[t], hh[t]);
  }
}

// ---------------- merged prep: BN finalize (block 0) + GAT pack (1..12) + FC pack (13..33) ----------------
struct PrepArgs {
  const float *sums, *gamma, *beta;
  const float *We[3], *ae[3];
  const float *gw[3];
  const float *fw[5], *fb[5];
  float *misc; short *W0, *W1, *W2; short *F0, *F1, *F2; float *bpack;
  int n;
};

__global__ __launch_bounds__(256) void k_prep(PrepArgs pa){
  int t = threadIdx.x;
  if (blockIdx.x == 0){
    if (t < D){
      float mean = pa.sums[t] / (float)pa.n;
      float var  = pa.sums[D + t] / (float)pa.n - mean * mean;
      float inv  = rsqrtf(var + 1e-5f);
      float sc = pa.gamma[t] * inv;
      pa.misc[t] = sc;
      pa.misc[D + t] = pa.beta[t] - mean * sc;
    } else if (t >= D && t < D + 3){
      int l = t - D;
      float c = 0.f;
      for (int d = 0; d < D; d++) c += pa.We[l][d] * pa.ae[l][d];
      pa.misc[2 * D + l] = c;
    }
  } else if (blockIdx.x <= 12){
    int tid = (blockIdx.x - 1) * 256 + t;
    if (tid >= 3 * 960) return;
    int L = tid & 63;
    int ct = (tid >> 6) % 15;
    int lay = tid / 960;
    const float* w = pa.gw[lay];
    int c = ct / 5, tt = ct % 5;
    int nn = tt * 16 + (L & 15);
    int kb = c * 32 + (L >> 4) * 8;
    #pragma unroll
    for (int j = 0; j < 8; j++){
      int k = kb + j;
      float v = (k < D && nn < D) ? w[k * D + nn] : 0.f;
      unsigned short b0 = bf16r(v);  float f0 = bf16f(b0);
      float r1 = v - f0;
      unsigned short b1 = bf16r(r1); float f1 = bf16f(b1);
      unsigned short b2 = bf16r(r1 - f1);
      pa.W0[tid * 8 + j] = (short)b0;
      pa.W1[tid * 8 + j] = (short)b1;
      pa.W2[tid * 8 + j] = (short)b2;
    }
  } else {
    int tid = (blockIdx.x - 13) * 256 + t;
    if (tid < 5 * 960){
      int L = tid & 63;
      int ct = (tid >> 6) % 15;
      int lay = tid / 960;
      const float* w = pa.fw[lay];
      int ncol = (lay == 4) ? 22 : D;
      int c = ct / 5, tt = ct % 5;
      int nn = tt * 16 + (L & 15);
      int kb = c * 32 + (L >> 4) * 8;
      #pragma unroll
      for (int j = 0; j < 8; j++){
        int k = kb + j;
        float v = (k < D && nn < ncol) ? w[k * ncol + nn] : 0.f;
        unsigned short b0 = bf16r(v);  float f0 = bf16f(b0);
        float r1 = v - f0;
        unsigned short b1 = bf16r(r1); float f1 = bf16f(b1);
        unsigned short b2 = bf16r(r1 - f1);
        pa.F0[tid * 8 + j] = (short)b0;
        pa.F1[tid * 8 + j] = (short)b1;
        pa.F2[tid * 8 + j] = (short)b2;
      }
    } else if (tid < 5 * 960 + 400){
      int i = tid - 5 * 960;
      int lay = i / 80, col = i % 80;
      int ncol = (lay == 4) ? 22 : D;
      pa.bpack[i] = (col < ncol) ? pa.fb[lay][col] : 0.f;
    }
  }
}

// ---------------- CSR build: binned counting sort ----------------
__global__ void k_bscan(const int* __restrict__ bhist, int* __restrict__ bbase,
                        int* __restrict__ gcur, int* __restrict__ rowptr, int N, int E){
  __shared__ int sh[256];
  int t = threadIdx.x;
  int v = bhist[t];
  sh[t] = v; __syncthreads();
  for (int o = 1; o < 256; o <<= 1){
    int u = (t >= o) ? sh[t - o] : 0;
    __syncthreads();
    sh[t] += u;
    __syncthreads();
  }
  int ex = sh[t] - v;
  bbase[t] = ex;
  gcur[t] = ex;
  if (t == 255){ bbase[256] = sh[255]; rowptr[N] = E; }
}

#define PCHUNK 4096
__global__ __launch_bounds__(256) void k_part(const int* __restrict__ src, const int* __restrict__ dst,
                                              const float* __restrict__ ew,
                                              int* __restrict__ gcur, int2* __restrict__ tmp, int E){
  __shared__ int hist[256];
  __shared__ int base[256];
  int t = threadIdx.x;
  int e0 = blockIdx.x * PCHUNK;
  int eend = min(E, e0 + PCHUNK);
  hist[t] = 0;
  __syncthreads();
  for (int e = e0 + t; e < eend; e += 256)
    atomicAdd(&hist[dst[e] >> 8], 1);
  __syncthreads();
  if (hist[t] > 0) base[t] = atomicAdd(&gcur[t], hist[t]);
  hist[t] = 0;
  __syncthreads();
  for (int e = e0 + t; e < eend; e += 256){
    int d = dst[e];
    int b = d >> 8;
    int off = atomicAdd(&hist[b], 1);
    tmp[base[b] + off] = make_int2((src[e] & 0xffff) | ((d & 255) << 16), __float_as_int(ew[e]));
  }
}

__global__ __launch_bounds__(256) void k_bsort(const int2* __restrict__ tmp, const int* __restrict__ bbase,
                                               int2* __restrict__ epair, int* __restrict__ rowptr, int N){
  __shared__ int2 ebuf[CAP];
  __shared__ int lcnt[256];
  __shared__ int sc[256];
  __shared__ int lcur[256];
  int b = blockIdx.x, t = threadIdx.x;
  int s0 = bbase[b], s1 = bbase[b + 1];
  int cnt = s1 - s0;
  lcnt[t] = 0;
  __syncthreads();
  for (int j = t; j < cnt; j += 256){
    int2 e = tmp[s0 + j];
    if (j < CAP) ebuf[j] = e;
    atomicAdd(&lcnt[(e.x >> 16) & 255], 1);
  }
  __syncthreads();
  int v = lcnt[t];
  sc[t] = v; __syncthreads();
  for (int o = 1; o < 256; o <<= 1){
    int u = (t >= o) ? sc[t - o] : 0;
    __syncthreads();
    sc[t] += u;
    __syncthreads();
  }
  int ex = sc[t] - v;
  int node = (b << 8) + t;
  if (node < N) rowptr[node] = s0 + ex;
  lcur[t] = ex;
  __syncthreads();
  for (int j = t; j < cnt; j += 256){
    int2 e = (j < CAP) ? ebuf[j] : tmp[s0 + j];
    int i = (e.x >> 16) & 255;
    int p = atomicAdd(&lcur[i], 1);
    epair[s0 + p] = make_int2(e.x & 0xffff, e.y);
  }
}

// ---------------- GAT GEMM via 3-term bf16 MFMA; optional fused BN on input ----------------
template<bool BN_IN>
__global__ __launch_bounds__(256) void k_mm(const float* __restrict__ X,
    const short* __restrict__ W0, const short* __restrict__ W1, const short* __restrict__ W2,
    const float* __restrict__ att_s, const float* __restrict__ att_d,
    const float* __restrict__ bn,
    float* __restrict__ Y, float* __restrict__ a_src, float* __restrict__ a_dst, int n){
  const int wv = threadIdx.x >> 6, L = threadIdx.x & 63;
  const int quad = L >> 4, m = L & 15;
  const int row0 = blockIdx.x * 64 + wv * 16;
  const int lrow = min(row0 + m, n - 1);
  f4v acc[5];
  #pragma unroll
  for (int t = 0; t < 5; t++) acc[t] = (f4v){0.f,0.f,0.f,0.f};

  #pragma unroll
  for (int c = 0; c < 3; c++){
    float xv[8];
    if (c < 2){
      if (BN_IN){
        const float* hr = X + (size_t)lrow * D + c * 32 + quad * 8;
        #pragma unroll
        for (int j = 0; j < 8; j += 2){
          float2 hv = *(const float2*)(hr + j);
          int col = c * 32 + quad * 8 + j;
          xv[j]     = hv.x * bn[col]     + bn[D + col];
          xv[j + 1] = hv.y * bn[col + 1] + bn[D + col + 1];
        }
      } else {
        const float* xr = X + (size_t)lrow * SP;
        float4 p0 = *(const float4*)&xr[c * 32 + quad * 8];
        float4 p1 = *(const float4*)&xr[c * 32 + quad * 8 + 4];
        xv[0] = p0.x; xv[1] = p0.y; xv[2] = p0.z; xv[3] = p0.w;
        xv[4] = p1.x; xv[5] = p1.y; xv[6] = p1.z; xv[7] = p1.w;
      }
    } else {
      #pragma unroll
      for (int j = 0; j < 8; j++) xv[j] = 0.f;
      if (quad == 0){
        if (BN_IN){
          float2 hv = *(const float2*)(X + (size_t)lrow * D + 64);
          xv[0] = hv.x * bn[64] + bn[D + 64];
          xv[1] = hv.y * bn[65] + bn[D + 65];
        } else {
          float4 p0 = *(const float4*)&X[(size_t)lrow * SP + 64];  // cols 66,67 stored zeros
          xv[0] = p0.x; xv[1] = p0.y; xv[2] = p0.z; xv[3] = p0.w;
        }
      }
    }
    s8v a0, a1, a2;
    split8t(xv, a0, a1, a2);
    const short* b0p = W0 + (c * 5) * 512 + L * 8;
    const short* b1p = W1 + (c * 5) * 512 + L * 8;
    const short* b2p = W2 + (c * 5) * 512 + L * 8;
    #pragma unroll
    for (int t = 0; t < 5; t++){
      s8v b0v = *(const s8v*)(b0p + t * 512);
      s8v b1v = *(const s8v*)(b1p + t * 512);
      s8v b2v = *(const s8v*)(b2p + t * 512);
      MM6(acc[t], a0, a1, a2, b0v, b1v, b2v)
    }
  }

  float ps[4] = {0.f,0.f,0.f,0.f}, pd[4] = {0.f,0.f,0.f,0.f};
  #pragma unroll
  for (int t = 0; t < 5; t++){
    int col = t * 16 + m;
    float as_v = 0.f, ad_v = 0.f;
    if (col < D){ as_v = att_s[col]; ad_v = att_d[col]; }
    #pragma unroll
    for (int r = 0; r < 4; r++){
      ps[r] += acc[t][r] * as_v;
      pd[r] += acc[t][r] * ad_v;
    }
  }
  #pragma unroll
  for (int r = 0; r < 4; r++){
    int rw = row0 + quad * 4 + r;
    if (rw < n){
      float* yr = Y + (size_t)rw * SP;
      #pragma unroll
      for (int t = 0; t < 4; t++) yr[t * 16 + m] = acc[t][r];
      if (m < 4) yr[64 + m] = (m < 2) ? acc[4][r] : 0.f;
    }
  }
  #pragma unroll
  for (int o = 1; o <= 8; o <<= 1){
    #pragma unroll
    for (int r = 0; r < 4; r++){
      ps[r] += __shfl_xor(ps[r], o);
      pd[r] += __shfl_xor(pd[r], o);
    }
  }
  if (m == 0){
    #pragma unroll
    for (int r = 0; r < 4; r++){
      int rw = row0 + quad * 4 + r;
      if (rw < n){ a_src[rw] = ps[r]; a_dst[rw] = pd[r]; }
    }
  }
}

// ---------------- Fused 5-layer FC head: wave-private LDS bounce, NO block barriers ----------------
// Correctness: each wave touches only xs[wv]; DS ops complete in order within a wave,
// so a compiler-only memory barrier (no instruction) suffices between write and next read.
#define FST 84
__global__ __launch_bounds__(256) void k_fcmm(const float* __restrict__ X,
    const short* __restrict__ W0, const short* __restrict__ W1, const short* __restrict__ W2,
    const float* __restrict__ bpack, float* __restrict__ out, int n){
  __shared__ __align__(16) float xs[4][16][FST];
  const int wv = threadIdx.x >> 6, L = threadIdx.x & 63;
  const int quad = L >> 4, m = L & 15;
  const int row0 = blockIdx.x * 64 + wv * 16;
  const int lrow = min(row0 + m, n - 1);
  const float* xr = X + (size_t)lrow * SP;

  for (int l = 0; l < 5; l++){
    const int NTl = (l == 4) ? 2 : 5;
    f4v acc[5];
    #pragma unroll
    for (int t = 0; t < 5; t++) acc[t] = (f4v){0.f,0.f,0.f,0.f};
    #pragma unroll
    for (int c = 0; c < 3; c++){
      float xv[8];
      if (l == 0){
        if (c < 2){
          float4 p0 = *(const float4*)&xr[c * 32 + quad * 8];
          float4 p1 = *(const float4*)&xr[c * 32 + quad * 8 + 4];
          xv[0] = p0.x; xv[1] = p0.y; xv[2] = p0.z; xv[3] = p0.w;
          xv[4] = p1.x; xv[5] = p1.y; xv[6] = p1.z; xv[7] = p1.w;
        } else {
          float4 p0 = make_float4(0.f, 0.f, 0.f, 0.f);
          if (quad == 0) p0 = *(const float4*)&xr[64];
          xv[0] = p0.x; xv[1] = p0.y; xv[2] = p0.z; xv[3] = p0.w;
          xv[4] = 0.f; xv[5] = 0.f; xv[6] = 0.f; xv[7] = 0.f;
        }
      } else {
        if (c == 2 && quad >= 2){
          #pragma unroll
          for (int j = 0; j < 8; j++) xv[j] = 0.f;
        } else {
          float4 p0 = *(const float4*)&xs[wv][m][c * 32 + quad * 8];
          float4 p1 = *(const float4*)&xs[wv][m][c * 32 + quad * 8 + 4];
          xv[0] = p0.x; xv[1] = p0.y; xv[2] = p0.z; xv[3] = p0.w;
          xv[4] = p1.x; xv[5] = p1.y; xv[6] = p1.z; xv[7] = p1.w;
        }
      }
      s8v a0, a1, a2;
      split8t(xv, a0, a1, a2);
      const short* b0p = W0 + ((l * 3 + c) * 5) * 512 + L * 8;
      const short* b1p = W1 + ((l * 3 + c) * 5) * 512 + L * 8;
      const short* b2p = W2 + ((l * 3 + c) * 5) * 512 + L * 8;
      for (int t = 0; t < NTl; t++){
        s8v b0v = *(const s8v*)(b0p + t * 512);
        s8v b1v = *(const s8v*)(b1p + t * 512);
        s8v b2v = *(const s8v*)(b2p + t * 512);
        MM6(acc[t], a0, a1, a2, b0v, b1v, b2v)
      }
    }
    if (l < 4){
      // reads of xs (above) feed acc -> writes below depend on acc: RAW chain orders them.
      #pragma unroll
      for (int t = 0; t < 5; t++){
        int col = t * 16 + m;
        float bv = bpack[l * 80 + col];   // padded cols: acc=0, bv=0 -> relu(0)=0
        #pragma unroll
        for (int r = 0; r < 4; r++){
          float v = acc[t][r] + bv;
          xs[wv][quad * 4 + r][col] = v > 0.f ? v : 0.f;
        }
      }
      __asm__ volatile("" ::: "memory");  // compiler fence: next layer's LDS reads stay after writes
    } else {
      #pragma unroll
      for (int t = 0; t < 2; t++){
        int col = t * 16 + m;
        #pragma unroll
        for (int r = 0; r < 4; r++){
          int rw = row0 + quad * 4 + r;
          if (col < 22 && rw < n) out[(size_t)rw * 22 + col] = acc[t][r] + bpack[4 * 80 + col];
        }
      }
    }
  }
}

// ---------------- GAT softmax + aggregate: one wave per dst node, 8 edges/iter ----------------
// All __shfl calls OUTSIDE divergent guards (ds_bpermute from inactive source lane is undefined).
__global__ __launch_bounds__(256) void k_agg(const float* __restrict__ y,
                                             const float* __restrict__ a_src, const float* __restrict__ a_dst,
                                             const int* __restrict__ rowptr, const int2* __restrict__ epair,
                                             const float* __restrict__ misc, int cidx,
                                             const float* __restrict__ bias,
                                             float* __restrict__ xout, int n){
  const int wid  = (int)((blockIdx.x * (size_t)blockDim.x + threadIdx.x) >> 6);
  const int lane = threadIdx.x & 63;
  if (wid >= n) return;
  const int beg = rowptr[wid];
  const int deg = rowptr[wid + 1] - beg;
  const float ce  = misc[2 * D + cidx];
  const float adn = a_dst[wid];
  const int g = lane >> 3, q = lane & 7;

  float4 accA = make_float4(0.f,0.f,0.f,0.f);
  float4 accB = make_float4(0.f,0.f,0.f,0.f);
  float2 tacc = make_float2(0.f,0.f);

  if (deg <= 64){
    int s = 0; float al = -INFINITY;
    bool act = lane < deg;
    if (act){
      int2 ep = epair[beg + lane];
      s = ep.x;
      al = lrelu(a_src[s] + adn + ce * __int_as_float(ep.y));
    }
    float mx = al;
    #pragma unroll
    for (int o = 32; o; o >>= 1) mx = fmaxf(mx, __shfl_xor(mx, o));
    float ex = act ? __expf(al - mx) : 0.f;
    float sum = ex;
    #pragma unroll
    for (int o = 32; o; o >>= 1) sum += __shfl_xor(sum, o);
    float coef = ex * (1.f / (sum + 1e-16f));
    for (int e0 = 0; e0 < deg; e0 += 8){
      int e = e0 + g;
      int   st = __shfl(s, e);
      float ct = __shfl(coef, e);
      if (e < deg){
        const float* row = y + (size_t)st * SP;
        float4 y0 = *(const float4*)&row[4 * q];
        float4 y1 = *(const float4*)&row[32 + 4 * q];
        fma4(accA, ct, y0);
        fma4(accB, ct, y1);
        if (q == 0){
          float2 tv = *(const float2*)&row[64];
          tacc.x += ct * tv.x; tacc.y += ct * tv.y;
        }
      }
    }
  } else {
    float mx = -INFINITY;
    for (int j0 = 0; j0 < deg; j0 += 64){
      int j = j0 + lane;
      if (j < deg){
        int2 ep = epair[beg + j];
        mx = fmaxf(mx, lrelu(a_src[ep.x] + adn + ce * __int_as_float(ep.y)));
      }
    }
    #pragma unroll
    for (int o = 32; o; o >>= 1) mx = fmaxf(mx, __shfl_xor(mx, o));
    float sum = 0.f;
    for (int j0 = 0; j0 < deg; j0 += 64){
      int j = j0 + lane;
      if (j < deg){
        int2 ep = epair[beg + j];
        sum += __expf(lrelu(a_src[ep.x] + adn + ce * __int_as_float(ep.y)) - mx);
      }
    }
    #pragma unroll
    for (int o = 32; o; o >>= 1) sum += __shfl_xor(sum, o);
    float inv = 1.f / (sum + 1e-16f);
    for (int j0 = 0; j0 < deg; j0 += 64){
      int cnt = min(64, deg - j0);
      int s = 0; float ex = 0.f;
      if (lane < cnt){
        int2 ep = epair[beg + j0 + lane];
        s = ep.x;
        ex = __expf(lrelu(a_src[s] + adn + ce * __int_as_float(ep.y)) - mx);
      }
      float coef = ex * inv;
      for (int e0 = 0; e0 < cnt; e0 += 8){
        int e = e0 + g;
        int   st = __shfl(s, e);
        float ct = __shfl(coef, e);
        if (e < cnt){
          const float* row = y + (size_t)st * SP;
          float4 y0 = *(const float4*)&row[4 * q];
          float4 y1 = *(const float4*)&row[32 + 4 * q];
          fma4(accA, ct, y0);
          fma4(accB, ct, y1);
          if (q == 0){
            float2 tv = *(const float2*)&row[64];
            tacc.x += ct * tv.x; tacc.y += ct * tv.y;
          }
        }
      }
    }
  }

  #pragma unroll
  for (int o = 8; o <= 32; o <<= 1){
    accA.x += __shfl_xor(accA.x, o); accA.y += __shfl_xor(accA.y, o);
    accA.z += __shfl_xor(accA.z, o); accA.w += __shfl_xor(accA.w, o);
    accB.x += __shfl_xor(accB.x, o); accB.y += __shfl_xor(accB.y, o);
    accB.z += __shfl_xor(accB.z, o); accB.w += __shfl_xor(accB.w, o);
    tacc.x += __shfl_xor(tacc.x, o); tacc.y += __shfl_xor(tacc.y, o);
  }
  float* orow = xout + (size_t)wid * SP;
  if (lane < 8){
    float4 v;
    v.x = accA.x + bias[4*lane+0]; v.x = v.x > 0.f ? v.x : 0.f;
    v.y = accA.y + bias[4*lane+1]; v.y = v.y > 0.f ? v.y : 0.f;
    v.z = accA.z + bias[4*lane+2]; v.z = v.z > 0.f ? v.z : 0.f;
    v.w = accA.w + bias[4*lane+3]; v.w = v.w > 0.f ? v.w : 0.f;
    *(float4*)&orow[4 * lane] = v;
  } else if (lane < 16){
    int qq = lane - 8;
    float4 v;
    v.x = accB.x + bias[32+4*qq+0]; v.x = v.x > 0.f ? v.x : 0.f;
    v.y = accB.y + bias[32+4*qq+1]; v.y = v.y > 0.f ? v.y : 0.f;
    v.z = accB.z + bias[32+4*qq+2]; v.z = v.z > 0.f ? v.z : 0.f;
    v.w = accB.w + bias[32+4*qq+3]; v.w = v.w > 0.f ? v.w : 0.f;
    *(float4*)&orow[32 + 4 * qq] = v;
  }
  if (lane == 0){
    float4 tv;
    tv.x = tacc.x + bias[64]; tv.x = tv.x > 0.f ? tv.x : 0.f;
    tv.y = tacc.y + bias[65]; tv.y = tv.y > 0.f ? tv.y : 0.f;
    tv.z = 0.f; tv.w = 0.f;
    *(float4*)&orow[64] = tv;
  }
}

// ---------------- launch ----------------
extern "C" void kernel_launch(void* const* d_in, const int* in_sizes, int n_in,
                              void* d_out, int out_size, void* d_ws, size_t ws_size,
                              hipStream_t stream){
  const float* h     = (const float*)d_in[0];
  const int*   ei    = (const int*)  d_in[1];
  const float* ew    = (const float*)d_in[2];
  const float* gamma = (const float*)d_in[3];
  const float* beta  = (const float*)d_in[4];
  const float *Wl[3], *bl[3], *asl[3], *adl[3], *Wel[3], *ael[3];
  int idx = 5;
  for (int l = 0; l < 3; l++){
    Wl[l]  = (const float*)d_in[idx++];
    bl[l]  = (const float*)d_in[idx++];
    asl[l] = (const float*)d_in[idx++];
    adl[l] = (const float*)d_in[idx++];
    Wel[l] = (const float*)d_in[idx++];
    ael[l] = (const float*)d_in[idx++];
  }
  const float *fw[5], *fb[5];
  for (int l = 0; l < 5; l++){ fw[l] = (const float*)d_in[idx++]; fb[l] = (const float*)d_in[idx++]; }

  int N = in_sizes[0] / D;
  int E = in_sizes[1] / 2;
  const int* src  = ei;
  const int* dstp = ei + E;

  char* base = (char*)d_ws;
  size_t o = 0;
  auto alloc = [&](size_t b){ size_t r = o; o += (b + 255) & ~(size_t)255; return r; };
  float*  bufA   = (float*)(base + alloc((size_t)N * SP * 4));
  float*  bufB   = (float*)(base + alloc((size_t)N * SP * 4));
  float*  a_src  = (float*)(base + alloc((size_t)N * 4));
  float*  a_dst  = (float*)(base + alloc((size_t)N * 4));
  float*  misc   = (float*)(base + alloc(512 * 4));
  float*  sums   = (float*)(base + alloc(2 * D * 4));
  int*    rowptr = (int*)  (base + alloc((size_t)(N + 1) * 4));
  int*    bhist  = (int*)  (base + alloc(256 * 4));
  int*    bbase  = (int*)  (base + alloc(257 * 4));
  int*    gcur   = (int*)  (base + alloc(256 * 4));
  int2*   epair  = (int2*) (base + alloc((size_t)E * 8));
  short*  W0p    = (short*)(base + alloc(3 * 7680 * 2));
  short*  W1p    = (short*)(base + alloc(3 * 7680 * 2));
  short*  W2p    = (short*)(base + alloc(3 * 7680 * 2));
  short*  FW0p   = (short*)(base + alloc(5 * 7680 * 2));
  short*  FW1p   = (short*)(base + alloc(5 * 7680 * 2));
  short*  FW2p   = (short*)(base + alloc(5 * 7680 * 2));
  float*  bpack  = (float*)(base + alloc(400 * 4));
  int2*   tmp    = (int2*)bufB;   // alias: bufB unused until first k_mm

  hipMemsetAsync(sums, 0, 2 * D * 4, stream);
  hipMemsetAsync(bhist, 0, 256 * 4, stream);

  k_stats_hist<<<512, 256, 0, stream>>>(h, dstp, sums, bhist, N, E);

  PrepArgs pa;
  pa.sums = sums; pa.gamma = gamma; pa.beta = beta;
  for (int l = 0; l < 3; l++){ pa.We[l] = Wel[l]; pa.ae[l] = ael[l]; pa.gw[l] = Wl[l]; }
  for (int l = 0; l < 5; l++){ pa.fw[l] = fw[l]; pa.fb[l] = fb[l]; }
  pa.misc = misc; pa.W0 = W0p; pa.W1 = W1p; pa.W2 = W2p;
  pa.F0 = FW0p; pa.F1 = FW1p; pa.F2 = FW2p; pa.bpack = bpack; pa.n = N;
  k_prep<<<34, 256, 0, stream>>>(pa);

  int NB = (N + 255) >> 8;
  k_bscan<<<1, 256, 0, stream>>>(bhist, bbase, gcur, rowptr, N, E);
  k_part<<<(E + PCHUNK - 1) / PCHUNK, 256, 0, stream>>>(src, dstp, ew, gcur, tmp, E);
  k_bsort<<<NB, 256, 0, stream>>>(tmp, bbase, epair, rowptr, N);

  int gb = (N + 63) / 64;
  int ab = (N + 3) / 4;

  // layer 1: BN fused into the GEMM's A-load (reads h directly)
  k_mm<true ><<<gb, 256, 0, stream>>>(h,    W0p + 0 * 7680, W1p + 0 * 7680, W2p + 0 * 7680,
                                      asl[0], adl[0], misc, bufB, a_src, a_dst, N);
  k_agg<<<ab, 256, 0, stream>>>(bufB, a_src, a_dst, rowptr, epair, misc, 0, bl[0], bufA, N);
  k_mm<false><<<gb, 256, 0, stream>>>(bufA, W0p + 1 * 7680, W1p + 1 * 7680, W2p + 1 * 7680,
                                      asl[1], adl[1], misc, bufB, a_src, a_dst, N);
  k_agg<<<ab, 256, 0, stream>>>(bufB, a_src, a_dst, rowptr, epair, misc, 1, bl[1], bufA, N);
  k_mm<false><<<gb, 256, 0, stream>>>(bufA, W0p + 2 * 7680, W1p + 2 * 7680, W2p + 2 * 7680,
                                      asl[2], adl[2], misc, bufB, a_src, a_dst, N);
  k_agg<<<ab, 256, 0, stream>>>(bufB, a_src, a_dst, rowptr, epair, misc, 2, bl[2], bufA, N);

  k_fcmm<<<gb, 256, 0, stream>>>(bufA, FW0p, FW1p, FW2p, bpack, (float*)d_out, N);
}